// Round 1
// baseline (1054.736 us; speedup 1.0000x reference)
//
#include <hip/hip_runtime.h>

using half4  = __attribute__((ext_vector_type(4))) _Float16;
using half8  = __attribute__((ext_vector_type(8))) _Float16;
using floatx4 = __attribute__((ext_vector_type(4))) float;

__device__ __forceinline__ void gl_lds16(const _Float16* g, _Float16* l)
{
  __builtin_amdgcn_global_load_lds(
      (const __attribute__((address_space(1))) void*)g,
      (__attribute__((address_space(3))) void*)l, 16, 0, 0);
}

// ---------------- MFMA fp16 GEMM (128x128 tile, BK=32, seg-XOR swizzled)
__global__ __launch_bounds__(256) void gemm_h(
    const _Float16* __restrict__ A, const _Float16* __restrict__ Bt,
    const float* __restrict__ bias, _Float16* __restrict__ C,
    int M, int N, int K, int ldC, int relu)
{
  __shared__ _Float16 As[128 * 32];
  __shared__ _Float16 Bs[128 * 32];
  int tid = threadIdx.x;
  int lane = tid & 63, wave = tid >> 6;
  long bm0 = (long)blockIdx.y * 128;
  int bn0 = blockIdx.x * 128;
  int wm = (wave & 1) * 64, wn = (wave >> 1) * 64;
  int srow = wave * 16 + (lane >> 2);
  int scol = (((lane & 3) ^ ((lane >> 3) & 3)) * 8);
  const _Float16* aA0 = A + (bm0 + srow) * (long)K + scol;
  const _Float16* aA1 = aA0 + 64 * (long)K;
  const _Float16* aB0 = Bt + (bn0 + srow) * (long)K + scol;
  const _Float16* aB1 = aB0 + 64 * (long)K;
  _Float16* lA0 = As + wave * 512;
  _Float16* lA1 = As + 2048 + wave * 512;
  _Float16* lB0 = Bs + wave * 512;
  _Float16* lB1 = Bs + 2048 + wave * 512;
  int mrow = lane & 15, quad = lane >> 4;
  int cofs = (quad ^ ((mrow >> 1) & 3)) * 8;
  floatx4 acc[4][4];
#pragma unroll
  for (int i = 0; i < 4; ++i)
#pragma unroll
    for (int j = 0; j < 4; ++j) acc[i][j] = (floatx4){0.f, 0.f, 0.f, 0.f};

  for (int kt = 0; kt < K; kt += 32) {
    __syncthreads();
    gl_lds16(aA0 + kt, lA0);
    gl_lds16(aA1 + kt, lA1);
    gl_lds16(aB0 + kt, lB0);
    gl_lds16(aB1 + kt, lB1);
    __syncthreads();
    half8 af[4], bf[4];
#pragma unroll
    for (int i = 0; i < 4; ++i)
      af[i] = *(const half8*)&As[(wm + 16 * i + mrow) * 32 + cofs];
#pragma unroll
    for (int j = 0; j < 4; ++j)
      bf[j] = *(const half8*)&Bs[(wn + 16 * j + mrow) * 32 + cofs];
#pragma unroll
    for (int i = 0; i < 4; ++i)
#pragma unroll
      for (int j = 0; j < 4; ++j)
        acc[i][j] = __builtin_amdgcn_mfma_f32_16x16x32_f16(af[i], bf[j], acc[i][j], 0, 0, 0);
  }
#pragma unroll
  for (int j = 0; j < 4; ++j) {
    int n = bn0 + wn + 16 * j + mrow;
    float bj = bias[n];
#pragma unroll
    for (int i = 0; i < 4; ++i) {
#pragma unroll
      for (int r = 0; r < 4; ++r) {
        long m = bm0 + wm + 16 * i + quad * 4 + r;
        float v = acc[i][j][r] + bj;
        if (relu) v = fmaxf(v, 0.f);
        C[m * (long)ldC + n] = (_Float16)v;
      }
    }
  }
}

// ---------------- MFMA fp16 GEMM (256x256 tile, BK=64, 8-wave, dbuf LDS,
//                  raw-barrier 4-phase schedule, counted vmcnt, XCD-banded remap)
__global__ __launch_bounds__(512, 2) void gemm8(
    const _Float16* __restrict__ A, const _Float16* __restrict__ Bt,
    const float* __restrict__ bias, _Float16* __restrict__ C,
    int MT, int NT, int K, int ldC, int relu)
{
  // LDS: 2 buffers x (A 256x64 + B 256x64) fp16 = 128 KB
  __shared__ _Float16 S[65536];
  int tid = threadIdx.x;
  int lane = tid & 63, wave = tid >> 6;
  int L = blockIdx.x;
  int xcd = L & 7, seq = L >> 3;
  int band = MT >> 3;                 // MT always a multiple of 8 here
  int mt = xcd * band + seq / NT;
  int nt = seq - (seq / NT) * NT;
  long bm0 = (long)mt * 256;
  int bn0 = nt * 256;
  // staging: per thread 4 A-loads + 4 B-loads per K-tile.
  // row = wave*32 + o*8 + (lane>>3); src col granule pre-swizzled (involution with read side)
  int r8 = lane >> 3, s8 = lane & 7;
  int scol = (s8 ^ r8) * 8;
  const _Float16* aA = A + (bm0 + wave * 32 + r8) * (long)K + scol;
  const _Float16* aB = Bt + (bn0 + wave * 32 + r8) * (long)K + scol;
  int wr = wave >> 2, wc = wave & 3;  // 2 x 4 wave grid, per-wave C = 128 x 64
  int ll = lane & 15, quad = lane >> 4;
  int lw = ll & 7;
  floatx4 acc[8][4];
#pragma unroll
  for (int i = 0; i < 8; ++i)
#pragma unroll
    for (int j = 0; j < 4; ++j) acc[i][j] = (floatx4){0.f, 0.f, 0.f, 0.f};

  int NTK = K >> 6;
  // prologue: stage K-tile 0 into buffer 0
#pragma unroll
  for (int o = 0; o < 4; ++o) {
    gl_lds16(aA + (long)(o * 8) * K, S + (wave * 32 + o * 8) * 64);
    gl_lds16(aB + (long)(o * 8) * K, S + 16384 + (wave * 32 + o * 8) * 64);
  }

  for (int t = 0; t < NTK; ++t) {
    _Float16* bufA = S + (t & 1) * 32768;
    _Float16* bufB = bufA + 16384;
    // issue next K-tile into the dead buffer, then counted wait: the 8 new
    // loads stay in flight across the wait + barrier (T4).
    if (t + 1 < NTK) {
      _Float16* nA = S + ((t + 1) & 1) * 32768;
      int kt = (t + 1) << 6;
#pragma unroll
      for (int o = 0; o < 4; ++o) {
        gl_lds16(aA + kt + (long)(o * 8) * K, nA + (wave * 32 + o * 8) * 64);
        gl_lds16(aB + kt + (long)(o * 8) * K, nA + 16384 + (wave * 32 + o * 8) * 64);
      }
      __builtin_amdgcn_sched_barrier(0);
      asm volatile("s_waitcnt vmcnt(8)" ::: "memory");
    } else {
      __builtin_amdgcn_sched_barrier(0);
      asm volatile("s_waitcnt vmcnt(0)" ::: "memory");
    }
    __builtin_amdgcn_sched_barrier(0);
    __builtin_amdgcn_s_barrier();   // raw: no vmcnt(0) drain of prefetch

    half8 aF[4][2];      // current A half: 4 frag-rows x 2 k-steps
    half8 bF[2][2][2];   // both B quarters: [ni][frag][k2]
    const _Float16* Abase = bufA + (wr * 128 + ll) * 64;
    const _Float16* Bbase = bufB + (wc * 64 + ll) * 64;

    // ---- phase 0: read A-half 0 + B-quarter 0; MFMA quadrant (0,0)
#pragma unroll
    for (int f = 0; f < 4; ++f)
#pragma unroll
      for (int k2 = 0; k2 < 2; ++k2)
        aF[f][k2] = *(const half8*)&Abase[(f * 16) * 64 + ((quad + 4 * k2) ^ lw) * 8];
#pragma unroll
    for (int j = 0; j < 2; ++j)
#pragma unroll
      for (int k2 = 0; k2 < 2; ++k2)
        bF[0][j][k2] = *(const half8*)&Bbase[(j * 16) * 64 + ((quad + 4 * k2) ^ lw) * 8];
    __builtin_amdgcn_s_barrier();
    __builtin_amdgcn_s_setprio(1);
#pragma unroll
    for (int f = 0; f < 4; ++f)
#pragma unroll
      for (int j = 0; j < 2; ++j)
#pragma unroll
        for (int k2 = 0; k2 < 2; ++k2)
          acc[f][j] = __builtin_amdgcn_mfma_f32_16x16x32_f16(aF[f][k2], bF[0][j][k2], acc[f][j], 0, 0, 0);
    __builtin_amdgcn_s_setprio(0);
    __builtin_amdgcn_s_barrier();

    // ---- phase 1: read B-quarter 1; MFMA quadrant (0,1)
#pragma unroll
    for (int j = 0; j < 2; ++j)
#pragma unroll
      for (int k2 = 0; k2 < 2; ++k2)
        bF[1][j][k2] = *(const half8*)&Bbase[(32 + j * 16) * 64 + ((quad + 4 * k2) ^ lw) * 8];
    __builtin_amdgcn_s_barrier();
    __builtin_amdgcn_s_setprio(1);
#pragma unroll
    for (int f = 0; f < 4; ++f)
#pragma unroll
      for (int j = 0; j < 2; ++j)
#pragma unroll
        for (int k2 = 0; k2 < 2; ++k2)
          acc[f][2 + j] = __builtin_amdgcn_mfma_f32_16x16x32_f16(aF[f][k2], bF[1][j][k2], acc[f][2 + j], 0, 0, 0);
    __builtin_amdgcn_s_setprio(0);
    __builtin_amdgcn_s_barrier();

    // ---- phase 2: read A-half 1; MFMA quadrant (1,0)
#pragma unroll
    for (int f = 0; f < 4; ++f)
#pragma unroll
      for (int k2 = 0; k2 < 2; ++k2)
        aF[f][k2] = *(const half8*)&Abase[(64 + f * 16) * 64 + ((quad + 4 * k2) ^ lw) * 8];
    __builtin_amdgcn_s_barrier();
    __builtin_amdgcn_s_setprio(1);
#pragma unroll
    for (int f = 0; f < 4; ++f)
#pragma unroll
      for (int j = 0; j < 2; ++j)
#pragma unroll
        for (int k2 = 0; k2 < 2; ++k2)
          acc[4 + f][j] = __builtin_amdgcn_mfma_f32_16x16x32_f16(aF[f][k2], bF[0][j][k2], acc[4 + f][j], 0, 0, 0);
    __builtin_amdgcn_s_setprio(0);
    __builtin_amdgcn_s_barrier();

    // ---- phase 3: MFMA quadrant (1,1) (all fragments already in regs)
    __builtin_amdgcn_s_setprio(1);
#pragma unroll
    for (int f = 0; f < 4; ++f)
#pragma unroll
      for (int j = 0; j < 2; ++j)
#pragma unroll
        for (int k2 = 0; k2 < 2; ++k2)
          acc[4 + f][2 + j] = __builtin_amdgcn_mfma_f32_16x16x32_f16(aF[f][k2], bF[1][j][k2], acc[4 + f][2 + j], 0, 0, 0);
    __builtin_amdgcn_s_setprio(0);
    // no trailing barrier needed: phase-2 end barrier guarantees every wave's
    // reads of the other buffer (prev tile) are long complete before the next
    // iteration's stage-issue overwrites it.
  }
#pragma unroll
  for (int fj = 0; fj < 4; ++fj) {
    int n = bn0 + wc * 64 + fj * 16 + ll;
    float bj = bias[n];
#pragma unroll
    for (int fi = 0; fi < 8; ++fi) {
#pragma unroll
      for (int r = 0; r < 4; ++r) {
        long m = bm0 + wr * 128 + fi * 16 + quad * 4 + r;
        float v = acc[fi][fj][r] + bj;
        if (relu) v = fmaxf(v, 0.f);
        C[m * (long)ldC + n] = (_Float16)v;
      }
    }
  }
}

// ---------------- MFMA fused attention (V prefetched into registers)
__global__ __launch_bounds__(256) void attn_h(
    const _Float16* __restrict__ Qp, int qs,
    const _Float16* __restrict__ Kp, const _Float16* __restrict__ Vp, int ks,
    _Float16* __restrict__ Op, int mode_ca, int l0, int rb0)
{
  __shared__ _Float16 KV[128 * 72];
  __shared__ _Float16 Ps[128 * 136];
  int tid = threadIdx.x;
  int lane = tid & 63, wave = tid >> 6;
  int ll = lane & 15, quad = lane >> 4;
  int idx = blockIdx.x;
  int n = idx & 7;
  int rl = idx >> 3;
  long obase = (long)rl * 128 * 512 + n * 64;
  long qoff, koff;
  if (!mode_ca) {
    qoff = (long)rl * 128 * qs + n * 64;
    koff = (long)rl * 128 * ks + n * 64;
  } else {
    int g = rb0 + rl;
    int a = g >> 5;
    int qblk = l0 ? (g & 31) : rl;
    qoff = (long)qblk * 128 * qs + n * 64;
    koff = (long)a * 128 * ks + n * 64;
  }
  // stage K tile; prefetch Q and V from global before first barrier
#pragma unroll
  for (int it = 0; it < 4; ++it) {
    int e = tid + it * 256;
    int r = e >> 3, c = (e & 7) * 8;
    *(half8*)&KV[r * 72 + c] = *(const half8*)&Kp[koff + (long)r * ks + c];
  }
  half8 aQ[2][2];
#pragma unroll
  for (int i = 0; i < 2; ++i)
#pragma unroll
    for (int k2 = 0; k2 < 2; ++k2)
      aQ[i][k2] = *(const half8*)&Qp[qoff + (long)(wave * 32 + i * 16 + ll) * qs
                                     + quad * 8 + k2 * 32];
  half8 vreg[4];
#pragma unroll
  for (int it = 0; it < 4; ++it) {
    int e = tid + it * 256;
    int vr = e >> 3, c = (e & 7) * 8;
    vreg[it] = *(const half8*)&Vp[koff + (long)vr * ks + c];
  }
  __syncthreads();
  floatx4 accS[2][8];
#pragma unroll
  for (int i = 0; i < 2; ++i)
#pragma unroll
    for (int j = 0; j < 8; ++j) accS[i][j] = (floatx4){0.f, 0.f, 0.f, 0.f};
#pragma unroll
  for (int k2 = 0; k2 < 2; ++k2) {
#pragma unroll
    for (int j = 0; j < 8; ++j) {
      half8 bK = *(const half8*)&KV[(j * 16 + ll) * 72 + quad * 8 + k2 * 32];
      accS[0][j] = __builtin_amdgcn_mfma_f32_16x16x32_f16(aQ[0][k2], bK, accS[0][j], 0, 0, 0);
      accS[1][j] = __builtin_amdgcn_mfma_f32_16x16x32_f16(aQ[1][k2], bK, accS[1][j], 0, 0, 0);
    }
  }
  float rinv[2][4];
#pragma unroll
  for (int i = 0; i < 2; ++i) {
#pragma unroll
    for (int r = 0; r < 4; ++r) {
      float mx = -1e30f;
#pragma unroll
      for (int j = 0; j < 8; ++j) {
        accS[i][j][r] *= 0.125f;
        mx = fmaxf(mx, accS[i][j][r]);
      }
#pragma unroll
      for (int off = 1; off < 16; off <<= 1) mx = fmaxf(mx, __shfl_xor(mx, off));
      float s = 0.f;
#pragma unroll
      for (int j = 0; j < 8; ++j) {
        float e = __expf(accS[i][j][r] - mx);
        accS[i][j][r] = e;
        s += e;
      }
#pragma unroll
      for (int off = 1; off < 16; off <<= 1) s += __shfl_xor(s, off);
      rinv[i][r] = 1.f / s;
      int prow = wave * 32 + i * 16 + quad * 4 + r;
#pragma unroll
      for (int j = 0; j < 8; ++j)
        Ps[prow * 136 + j * 16 + ll] = (_Float16)accS[i][j][r];
    }
  }
  __syncthreads();   // K reads done; Ps visible
  // write prefetched V transposed: Vt[h][seq] at KV[h*132 + seq]
#pragma unroll
  for (int it = 0; it < 4; ++it) {
    int e = tid + it * 256;
    int vr = e >> 3, c = (e & 7) * 8;
#pragma unroll
    for (int j = 0; j < 8; ++j) KV[(c + j) * 132 + vr] = vreg[it][j];
  }
  __syncthreads();
  floatx4 accO[2][4];
#pragma unroll
  for (int i = 0; i < 2; ++i)
#pragma unroll
    for (int j = 0; j < 4; ++j) accO[i][j] = (floatx4){0.f, 0.f, 0.f, 0.f};
#pragma unroll
  for (int k4 = 0; k4 < 4; ++k4) {
    half8 aP[2];
#pragma unroll
    for (int i = 0; i < 2; ++i)
      aP[i] = *(const half8*)&Ps[(wave * 32 + i * 16 + ll) * 136 + quad * 8 + k4 * 32];
#pragma unroll
    for (int jh = 0; jh < 4; ++jh) {
      int vb = (jh * 16 + ll) * 132 + quad * 8 + k4 * 32;
      half4 v0 = *(const half4*)&KV[vb];
      half4 v1 = *(const half4*)&KV[vb + 4];
      half8 bV = __builtin_shufflevector(v0, v1, 0, 1, 2, 3, 4, 5, 6, 7);
      accO[0][jh] = __builtin_amdgcn_mfma_f32_16x16x32_f16(aP[0], bV, accO[0][jh], 0, 0, 0);
      accO[1][jh] = __builtin_amdgcn_mfma_f32_16x16x32_f16(aP[1], bV, accO[1][jh], 0, 0, 0);
    }
  }
#pragma unroll
  for (int i = 0; i < 2; ++i)
#pragma unroll
    for (int jh = 0; jh < 4; ++jh)
#pragma unroll
      for (int r = 0; r < 4; ++r) {
        int m = wave * 32 + i * 16 + quad * 4 + r;
        Op[obase + (long)m * 512 + jh * 16 + ll] = (_Float16)(accO[i][jh][r] * rinv[i][r]);
      }
}

// ---------------- Residual + LayerNorm (rows of 512, fp32 math). One wave per row.
__global__ __launch_bounds__(256) void ln_h(
    const void* __restrict__ xin, int xf32, const _Float16* __restrict__ add,
    _Float16* __restrict__ out, const float* __restrict__ g,
    const float* __restrict__ bt, long row0, int bmask)
{
  int rl = blockIdx.x * 4 + (threadIdx.x >> 6);
  long row = row0 + rl;
  int lane = threadIdx.x & 63;
  long xr = (row & (long)bmask) * 512 + lane * 8;
  float v[8];
  if (xf32) {
    float4 a0 = *(const float4*)((const float*)xin + xr);
    float4 a1 = *(const float4*)((const float*)xin + xr + 4);
    v[0] = a0.x; v[1] = a0.y; v[2] = a0.z; v[3] = a0.w;
    v[4] = a1.x; v[5] = a1.y; v[6] = a1.z; v[7] = a1.w;
  } else {
    half8 h = *(const half8*)((const _Float16*)xin + xr);
#pragma unroll
    for (int i = 0; i < 8; ++i) v[i] = (float)h[i];
  }
  if (add) {
    half8 a = *(const half8*)&add[(long)rl * 512 + lane * 8];
#pragma unroll
    for (int i = 0; i < 8; ++i) v[i] += (float)a[i];
  }
  float s = 0.f, sq = 0.f;
#pragma unroll
  for (int i = 0; i < 8; ++i) { s += v[i]; sq += v[i] * v[i]; }
#pragma unroll
  for (int off = 1; off < 64; off <<= 1) {
    s += __shfl_xor(s, off);
    sq += __shfl_xor(sq, off);
  }
  float mean = s * (1.f / 512.f);
  float var = sq * (1.f / 512.f) - mean * mean;
  float rst = rsqrtf(var + 1e-6f);
  int c = lane * 8;
  float4 g0 = *(const float4*)&g[c], g1 = *(const float4*)&g[c + 4];
  float4 b0 = *(const float4*)&bt[c], b1 = *(const float4*)&bt[c + 4];
  float gg[8] = {g0.x, g0.y, g0.z, g0.w, g1.x, g1.y, g1.z, g1.w};
  float bb[8] = {b0.x, b0.y, b0.z, b0.w, b1.x, b1.y, b1.z, b1.w};
  half8 o;
#pragma unroll
  for (int i = 0; i < 8; ++i) o[i] = (_Float16)((v[i] - mean) * rst * gg[i] + bb[i]);
  *(half8*)&out[row * 512 + c] = o;
}

// ---------------- batched 512x512 transpose-convert (12 weights in one launch)
__global__ __launch_bounds__(256) void tconv512(
    const float* __restrict__ w0, const float* __restrict__ w1,
    const float* __restrict__ w2, const float* __restrict__ w3,
    const float* __restrict__ w4, const float* __restrict__ w5,
    _Float16* __restrict__ Wh)
{
  __shared__ float T[64][65];
  int z = blockIdx.z;
  int t = z >> 1, l = z & 1;
  const float* src;
  long off;
  switch (t) {
    case 0: src = w0; off = 0; break;
    case 1: src = w1; off = 262144; break;
    case 2: src = w2; off = 524288; break;
    case 3: src = w3; off = 1048576; break;
    case 4: src = w4; off = 1310720; break;
    default: src = w5; off = 1572864; break;
  }
  src += (long)l * 262144;
  _Float16* out = Wh + (long)l * 4194304 + off;
  int tx = threadIdx.x & 63, tg = threadIdx.x >> 6;
  int r0 = blockIdx.y * 64, c0 = blockIdx.x * 64;
#pragma unroll
  for (int i = 0; i < 16; ++i)
    T[tg + 4 * i][tx] = src[(long)(r0 + tg + 4 * i) * 512 + c0 + tx];
  __syncthreads();
#pragma unroll
  for (int i = 0; i < 16; ++i)
    out[(long)(c0 + tg + 4 * i) * 512 + r0 + tx] = (_Float16)T[tx][tg + 4 * i];
}

// ---------------- layered transpose-convert for FFN weights
__global__ __launch_bounds__(256) void tconvL(const float* __restrict__ in,
                                              _Float16* __restrict__ out, int Rr, int Cc,
                                              long ils, long ols)
{
  __shared__ float T[64][65];
  in += (long)blockIdx.z * ils;
  out += (long)blockIdx.z * ols;
  int tx = threadIdx.x & 63, tg = threadIdx.x >> 6;
  int r0 = blockIdx.y * 64, c0 = blockIdx.x * 64;
#pragma unroll
  for (int i = 0; i < 16; ++i)
    T[tg + 4 * i][tx] = in[(long)(r0 + tg + 4 * i) * Cc + c0 + tx];
  __syncthreads();
#pragma unroll
  for (int i = 0; i < 16; ++i)
    out[(long)(c0 + tg + 4 * i) * Rr + r0 + tx] = (_Float16)T[tx][tg + 4 * i];
}

// ---------------- batched wo conversion
__global__ void woconvB(const float* __restrict__ sa_wo, const float* __restrict__ ca_wo,
                        _Float16* __restrict__ Wh)
{
  int z = blockIdx.y;
  int s = z >> 1, l = z & 1;
  const float* wo = (s ? ca_wo : sa_wo) + (long)l * 262144;
  _Float16* out = Wh + (long)l * 4194304 + (s ? 1835008 : 786432);
  int o = blockIdx.x * 256 + threadIdx.x;  // 262144
  int d = o >> 9;
  int nh = o & 511;
  int n = nh >> 6, h = nh & 63;
  out[o] = (_Float16)wo[((long)(n << 9) + d) * 64 + h];
}

// ---------------- pack all biases in one launch
__global__ void packbias(const float* __restrict__ sa_bq, const float* __restrict__ sa_bk,
                         const float* __restrict__ sa_bv, const float* __restrict__ ca_bk,
                         const float* __restrict__ ca_bv, float* __restrict__ Bqkv,
                         float* __restrict__ Bkv)
{
  int i = blockIdx.x * 256 + threadIdx.x;
  if (i >= 5120) return;
  int reg = i >> 9, idx = i & 511;
  int l = reg / 5, r = reg % 5;
  int lo = l * 512;
  switch (r) {
    case 0: Bqkv[l * 1536 + idx] = sa_bq[lo + idx]; break;
    case 1: Bqkv[l * 1536 + 512 + idx] = sa_bk[lo + idx]; break;
    case 2: Bqkv[l * 1536 + 1024 + idx] = sa_bv[lo + idx]; break;
    case 3: Bkv[l * 1024 + idx] = ca_bk[lo + idx]; break;
    default: Bkv[l * 1024 + 512 + idx] = ca_bv[lo + idx]; break;
  }
}

// ---------------- fused fp32->fp16 for c and q
__global__ void f2h2(const float* __restrict__ a, _Float16* __restrict__ oa, long na,
                     const float* __restrict__ bsrc, _Float16* __restrict__ ob, long nb)
{
  long i = blockIdx.x * 256L + threadIdx.x;
  if (i < na) oa[i] = (_Float16)a[i];
  else if (i < na + nb) ob[i - na] = (_Float16)bsrc[i - na];
}

// ---------------- fused pool(q fp32) + feature + normalize -> QN (8 x 256)
__global__ void featq_pool(const float* __restrict__ q, const float* __restrict__ W,
                           const float* __restrict__ bias, float* __restrict__ QN)
{
  __shared__ float sh[512];
  __shared__ float red[256];
  int a = blockIdx.x;
  int f = threadIdx.x;
  for (int dd = f; dd < 512; dd += 256) {
    const float* base = q + (long)a * 65536 + dd;
    float s = 0.f;
    for (int t = 1; t < 128; ++t) s += base[t * 512];
    sh[dd] = s * (1.f / 127.f);
  }
  __syncthreads();
  float acc = bias[f];
  for (int d = 0; d < 512; ++d) acc += sh[d] * W[d * 256 + f];
  red[f] = acc * acc;
  __syncthreads();
  for (int s = 128; s > 0; s >>= 1) {
    if (f < s) red[f] += red[f + s];
    __syncthreads();
  }
  float rn = rsqrtf(fmaxf(red[0], 1e-12f));
  QN[a * 256 + f] = acc * rn;
}

// ---------------- fused pool(X fp16) + feature + normalize + dot(QN) -> out (256)
__global__ void featc_pool(const _Float16* __restrict__ X, const float* __restrict__ W,
                           const float* __restrict__ bias, const float* __restrict__ QN,
                           float* __restrict__ out)
{
  __shared__ float sh[512];
  __shared__ float red[256];
  int ab = blockIdx.x;
  int f = threadIdx.x;
  for (int dd = f; dd < 512; dd += 256) {
    const _Float16* base = X + (long)ab * 65536 + dd;
    float s = 0.f;
    for (int t = 1; t < 128; ++t) s += (float)base[t * 512];
    sh[dd] = s * (1.f / 127.f);
  }
  __syncthreads();
  float acc = bias[f];
  for (int d = 0; d < 512; ++d) acc += sh[d] * W[d * 256 + f];
  red[f] = acc * acc;
  __syncthreads();
  for (int s = 128; s > 0; s >>= 1) {
    if (f < s) red[f] += red[f + s];
    __syncthreads();
  }
  float rn = rsqrtf(fmaxf(red[0], 1e-12f));
  float v = acc * rn * QN[(ab >> 5) * 256 + f];
  __syncthreads();
  red[f] = v;
  __syncthreads();
  for (int s = 128; s > 0; s >>= 1) {
    if (f < s) red[f] += red[f + s];
    __syncthreads();
  }
  if (f == 0) out[ab] = red[0];
}

extern "C" void kernel_launch(void* const* d_in, const int* in_sizes, int n_in,
                              void* d_out, int out_size, void* d_ws, size_t ws_size,
                              hipStream_t stream)
{
  (void)in_sizes; (void)n_in; (void)out_size;
  const float* c_in  = (const float*)d_in[0];
  const float* q_in  = (const float*)d_in[1];
  const float* sa_wq = (const float*)d_in[2];
  const float* sa_bq = (const float*)d_in[3];
  const float* sa_wk = (const float*)d_in[4];
  const float* sa_bk = (const float*)d_in[5];
  const float* sa_wv = (const float*)d_in[6];
  const float* sa_bv = (const float*)d_in[7];
  const float* sa_wo = (const float*)d_in[8];
  const float* sa_bo = (const float*)d_in[9];
  const float* ca_wq = (const float*)d_in[10];
  const float* ca_bq = (const float*)d_in[11];
  const float* ca_wk = (const float*)d_in[12];
  const float* ca_bk = (const float*)d_in[13];
  const float* ca_wv = (const float*)d_in[14];
  const float* ca_bv = (const float*)d_in[15];
  const float* ca_wo = (const float*)d_in[16];
  const float* ca_bo = (const float*)d_in[17];
  const float* ln1_g = (const float*)d_in[18];
  const float* ln1_b = (const float*)d_in[19];
  const float* ln2_g = (const float*)d_in[20];
  const float* ln2_b = (const float*)d_in[21];
  const float* ln3_g = (const float*)d_in[22];
  const float* ln3_b = (const float*)d_in[23];
  const float* ffn_w1 = (const float*)d_in[24];
  const float* ffn_b1 = (const float*)d_in[25];
  const float* ffn_w2 = (const float*)d_in[26];
  const float* ffn_b2 = (const float*)d_in[27];
  const float* lnf_g  = (const float*)d_in[28];
  const float* lnf_b  = (const float*)d_in[29];
  const float* feat_wq = (const float*)d_in[30];
  const float* feat_bq = (const float*)d_in[31];
  const float* feat_wc = (const float*)d_in[32];
  const float* feat_bc = (const float*)d_in[33];

  // ---- workspace layout
  char* p = (char*)d_ws;
  _Float16* Xh  = (_Float16*)p;  p += 33554432;  // 32768 x 512 fp16 residual stream
  _Float16* Xsh = (_Float16*)p;  p += 4194304;   //  4096 x 512 fp16 (layer-0 x)
  _Float16* Wh  = (_Float16*)p;  p += 16777216;  // fp16 weight arena (2 layers)
  _Float16* qh  = (_Float16*)p;  p += 1048576;   //  1024 x 512 fp16
  _Float16* KV0 = (_Float16*)p;  p += 2097152;   //  1024 x 1024 fp16 (K|V)
  float*    Bqkv = (float*)p;    p += 12288;
  float*    Bkv  = (float*)p;    p += 8192;
  float*    QN  = (float*)p;     p += 8192;
  const size_t fixed_b = (size_t)(p - (char*)d_ws);
  long R = 4096;
  if (ws_size >= fixed_b + 5120UL * 32768) R = 32768;
  else if (ws_size >= fixed_b + 5120UL * 16384) R = 16384;
  else if (ws_size >= fixed_b + 5120UL * 8192) R = 8192;
  _Float16* QKVc = (_Float16*)p; p += R * 3072;  // [R][1536]
  _Float16* Oc   = (_Float16*)p; p += R * 1024;  // [R][512]
  _Float16* Ac   = (_Float16*)p;                 // [R][512]
  _Float16* Hb = QKVc;            // FFN hidden [R][2048] spans QKVc+Oc (contiguous)
  const int MTR = (int)(R / 256);

  // ---- prep (6 launches)
  f2h2<<<10240, 256, 0, stream>>>(c_in, Xsh, 2097152, q_in, qh, 524288);
  tconv512<<<dim3(8, 8, 12), 256, 0, stream>>>(sa_wq, sa_wk, sa_wv, ca_wq, ca_wk, ca_wv, Wh);
  woconvB<<<dim3(1024, 4), 256, 0, stream>>>(sa_wo, ca_wo, Wh);
  tconvL<<<dim3(32, 8, 2), 256, 0, stream>>>(ffn_w1, Wh + 2097152, 512, 2048, 1048576, 4194304);
  tconvL<<<dim3(8, 32, 2), 256, 0, stream>>>(ffn_w2, Wh + 3145728, 2048, 512, 1048576, 4194304);
  packbias<<<20, 256, 0, stream>>>(sa_bq, sa_bk, sa_bv, ca_bk, ca_bv, Bqkv, Bkv);

  // =================== layer 0 (x rows = 4096) ===================
  {
    _Float16* Wl = Wh;
    gemm_h<<<dim3(12, 32), 256, 0, stream>>>(Xsh, Wl + 0, Bqkv, QKVc, 4096, 1536, 512, 1536, 0);
    attn_h<<<256, 256, 0, stream>>>(QKVc, 1536, QKVc + 512, QKVc + 1024, 1536, Oc, 0, 0, 0);
    gemm_h<<<dim3(4, 32), 256, 0, stream>>>(Oc, Wl + 786432, sa_bo, Ac, 4096, 512, 512, 512, 0);
    ln_h<<<1024, 256, 0, stream>>>(c_in, 1, Ac, Xsh, ln1_g, ln1_b, 0, 0x7FFFFFFF);
    gemm_h<<<dim3(4, 32), 256, 0, stream>>>(Xsh, Wl + 1048576, ca_bq, QKVc, 4096, 512, 512, 1536, 0);
    gemm_h<<<dim3(8, 8), 256, 0, stream>>>(qh, Wl + 1310720, Bkv, KV0, 1024, 1024, 512, 1024, 0);
    for (long c = 0; c < 32768; c += R) {
      attn_h<<<(R / 128) * 8, 256, 0, stream>>>(QKVc, 1536, KV0, KV0 + 512, 1024, Oc,
                                                1, 1, (int)(c / 128));
      gemm8<<<MTR * 2, 512, 0, stream>>>(Oc, Wl + 1835008, ca_bo, Ac, MTR, 2, 512, 512, 0);
      ln_h<<<R / 4, 256, 0, stream>>>(Xsh, 0, Ac, Xh, ln2_g, ln2_b, c, 4095);
      gemm8<<<MTR * 8, 512, 0, stream>>>(Xh + c * 512, Wl + 2097152,
                                         ffn_b1, Hb, MTR, 8, 512, 2048, 1);
      gemm8<<<MTR * 2, 512, 0, stream>>>(Hb, Wl + 3145728, ffn_b2, Ac, MTR, 2, 2048, 512, 0);
      ln_h<<<R / 4, 256, 0, stream>>>(Xh, 0, Ac, Xh, ln3_g, ln3_b, c, 0x7FFFFFFF);
    }
  }
  // =================== layer 1 (x rows = 32768) ===================
  {
    _Float16* Wl = Wh + 4194304;
    gemm_h<<<dim3(8, 8), 256, 0, stream>>>(qh, Wl + 1310720, Bkv + 1024, KV0, 1024, 1024, 512, 1024, 0);
    for (long c = 0; c < 32768; c += R) {
      _Float16* Xhc = Xh + c * 512;
      gemm8<<<MTR * 6, 512, 0, stream>>>(Xhc, Wl + 0, Bqkv + 1536, QKVc, MTR, 6, 512, 1536, 0);
      attn_h<<<(R / 128) * 8, 256, 0, stream>>>(QKVc, 1536, QKVc + 512, QKVc + 1024, 1536,
                                                Oc, 0, 0, 0);
      gemm8<<<MTR * 2, 512, 0, stream>>>(Oc, Wl + 786432, sa_bo + 512, Ac, MTR, 2, 512, 512, 0);
      ln_h<<<R / 4, 256, 0, stream>>>(Xh, 0, Ac, Xh, ln1_g + 512, ln1_b + 512, c, 0x7FFFFFFF);
      gemm8<<<MTR * 2, 512, 0, stream>>>(Xhc, Wl + 1048576, ca_bq + 512, QKVc, MTR, 2, 512, 1536, 0);
      attn_h<<<(R / 128) * 8, 256, 0, stream>>>(QKVc, 1536, KV0, KV0 + 512, 1024, Oc,
                                                1, 0, (int)(c / 128));
      gemm8<<<MTR * 2, 512, 0, stream>>>(Oc, Wl + 1835008, ca_bo + 512, Ac, MTR, 2, 512, 512, 0);
      ln_h<<<R / 4, 256, 0, stream>>>(Xh, 0, Ac, Xh, ln2_g + 512, ln2_b + 512, c, 0x7FFFFFFF);
      gemm8<<<MTR * 16, 512, 0, stream>>>(Xh + c * 512, Wl + 2097152,
                                          ffn_b1 + 2048, Hb, MTR, 8, 512, 2048, 1);
      gemm8<<<MTR * 2, 512, 0, stream>>>(Hb, Wl + 3145728, ffn_b2 + 512, Ac, MTR, 2, 2048, 512, 0);
      ln_h<<<R / 4, 256, 0, stream>>>(Xh, 0, Ac, Xh, ln3_g + 512, ln3_b + 512, c, 0x7FFFFFFF);
    }
  }
  // =================== final LN + fused pool/features/cosine ===================
  ln_h<<<8192, 256, 0, stream>>>(Xh, 0, nullptr, Xh, lnf_g, lnf_b, 0, 0x7FFFFFFF);
  featq_pool<<<8, 256, 0, stream>>>(q_in, feat_wq, feat_bq, QN);
  featc_pool<<<256, 256, 0, stream>>>(Xh, feat_wc, feat_bc, QN, (float*)d_out);
}

// Round 2
// 1001.370 us; speedup vs baseline: 1.0533x; 1.0533x over previous
//
#include <hip/hip_runtime.h>

using half4  = __attribute__((ext_vector_type(4))) _Float16;
using half8  = __attribute__((ext_vector_type(8))) _Float16;
using floatx4 = __attribute__((ext_vector_type(4))) float;

__device__ __forceinline__ void gl_lds16(const _Float16* g, _Float16* l)
{
  __builtin_amdgcn_global_load_lds(
      (const __attribute__((address_space(1))) void*)g,
      (__attribute__((address_space(3))) void*)l, 16, 0, 0);
}

__device__ __forceinline__ uint32_t lds_u32(const _Float16* p)
{
  return (uint32_t)(uintptr_t)(const __attribute__((address_space(3))) _Float16*)p;
}

// inline-asm LDS read: opaque to the compiler's waitcnt insertion (it would
// otherwise emit vmcnt(0) before LDS reads that might alias pending
// global_load_lds destinations, killing the counted-vmcnt pipeline).
template<int IMM>
__device__ __forceinline__ half8 dsr(uint32_t addr)
{
  half8 r;
  asm volatile("ds_read_b128 %0, %1 offset:%2" : "=v"(r) : "v"(addr), "i"(IMM));
  return r;
}

// rule #18: lgkmcnt fence for asm ds_reads must be followed by sched_barrier(0)
#define LGK0() do { asm volatile("s_waitcnt lgkmcnt(0)" ::: "memory"); \
                    __builtin_amdgcn_sched_barrier(0); } while (0)

// ---------------- MFMA fp16 GEMM (128x128 tile, BK=32, seg-XOR swizzled)
__global__ __launch_bounds__(256) void gemm_h(
    const _Float16* __restrict__ A, const _Float16* __restrict__ Bt,
    const float* __restrict__ bias, _Float16* __restrict__ C,
    int M, int N, int K, int ldC, int relu)
{
  __shared__ _Float16 As[128 * 32];
  __shared__ _Float16 Bs[128 * 32];
  int tid = threadIdx.x;
  int lane = tid & 63, wave = tid >> 6;
  long bm0 = (long)blockIdx.y * 128;
  int bn0 = blockIdx.x * 128;
  int wm = (wave & 1) * 64, wn = (wave >> 1) * 64;
  int srow = wave * 16 + (lane >> 2);
  int scol = (((lane & 3) ^ ((lane >> 3) & 3)) * 8);
  const _Float16* aA0 = A + (bm0 + srow) * (long)K + scol;
  const _Float16* aA1 = aA0 + 64 * (long)K;
  const _Float16* aB0 = Bt + (bn0 + srow) * (long)K + scol;
  const _Float16* aB1 = aB0 + 64 * (long)K;
  _Float16* lA0 = As + wave * 512;
  _Float16* lA1 = As + 2048 + wave * 512;
  _Float16* lB0 = Bs + wave * 512;
  _Float16* lB1 = Bs + 2048 + wave * 512;
  int mrow = lane & 15, quad = lane >> 4;
  int cofs = (quad ^ ((mrow >> 1) & 3)) * 8;
  floatx4 acc[4][4];
#pragma unroll
  for (int i = 0; i < 4; ++i)
#pragma unroll
    for (int j = 0; j < 4; ++j) acc[i][j] = (floatx4){0.f, 0.f, 0.f, 0.f};

  for (int kt = 0; kt < K; kt += 32) {
    __syncthreads();
    gl_lds16(aA0 + kt, lA0);
    gl_lds16(aA1 + kt, lA1);
    gl_lds16(aB0 + kt, lB0);
    gl_lds16(aB1 + kt, lB1);
    __syncthreads();
    half8 af[4], bf[4];
#pragma unroll
    for (int i = 0; i < 4; ++i)
      af[i] = *(const half8*)&As[(wm + 16 * i + mrow) * 32 + cofs];
#pragma unroll
    for (int j = 0; j < 4; ++j)
      bf[j] = *(const half8*)&Bs[(wn + 16 * j + mrow) * 32 + cofs];
#pragma unroll
    for (int i = 0; i < 4; ++i)
#pragma unroll
      for (int j = 0; j < 4; ++j)
        acc[i][j] = __builtin_amdgcn_mfma_f32_16x16x32_f16(af[i], bf[j], acc[i][j], 0, 0, 0);
  }
#pragma unroll
  for (int j = 0; j < 4; ++j) {
    int n = bn0 + wn + 16 * j + mrow;
    float bj = bias[n];
#pragma unroll
    for (int i = 0; i < 4; ++i) {
#pragma unroll
      for (int r = 0; r < 4; ++r) {
        long m = bm0 + wm + 16 * i + quad * 4 + r;
        float v = acc[i][j][r] + bj;
        if (relu) v = fmaxf(v, 0.f);
        C[m * (long)ldC + n] = (_Float16)v;
      }
    }
  }
}

// ---------------- MFMA fp16 GEMM (256x256 tile, BK=64, 8-wave, dbuf LDS,
//                  asm ds_read + counted vmcnt, 2 barriers/K-tile)
__global__ __launch_bounds__(512, 2) void gemm8(
    const _Float16* __restrict__ A, const _Float16* __restrict__ Bt,
    const float* __restrict__ bias, _Float16* __restrict__ C,
    int MT, int NT, int K, int ldC, int relu)
{
  __shared__ _Float16 S[65536];   // 2 x (A 256x64 + B 256x64) fp16 = 128 KB
  int tid = threadIdx.x;
  int lane = tid & 63, wave = tid >> 6;
  int L = blockIdx.x;
  int xcd = L & 7, seq = L >> 3;
  int band = MT >> 3;                 // MT always a multiple of 8 here
  int mt = xcd * band + seq / NT;
  int nt = seq - (seq / NT) * NT;
  long bm0 = (long)mt * 256;
  int bn0 = nt * 256;
  int r8 = lane >> 3, s8 = lane & 7;
  int scol = (s8 ^ r8) * 8;           // pre-swizzled global source seg
  const _Float16* aA = A + (bm0 + wave * 32 + r8) * (long)K + scol;
  const _Float16* aB = Bt + (bn0 + wave * 32 + r8) * (long)K + scol;
  int wr = wave >> 2, wc = wave & 3;  // 2 x 4 wave grid, per-wave C = 128 x 64
  int ll = lane & 15, quad = lane >> 4;
  int lw = ll & 7;
  // byte-unit LDS addresses for asm ds_read
  uint32_t aoff = lds_u32(S) + (uint32_t)(wr * 128 + ll) * 128u;
  uint32_t boff = lds_u32(S) + 32768u + (uint32_t)(wc * 64 + ll) * 128u;
  uint32_t x0 = (uint32_t)((quad ^ lw) * 16);
  uint32_t x1 = (uint32_t)(((quad + 4) ^ lw) * 16);
  floatx4 acc[8][4];
#pragma unroll
  for (int i = 0; i < 8; ++i)
#pragma unroll
    for (int j = 0; j < 4; ++j) acc[i][j] = (floatx4){0.f, 0.f, 0.f, 0.f};

  int NTK = K >> 6;
  // prologue: stage K-tile 0 into buffer 0
#pragma unroll
  for (int o = 0; o < 4; ++o) {
    gl_lds16(aA + (long)(o * 8) * K, S + (wave * 32 + o * 8) * 64);
    gl_lds16(aB + (long)(o * 8) * K, S + 16384 + (wave * 32 + o * 8) * 64);
  }

  for (int t = 0; t < NTK; ++t) {
    uint32_t db = (t & 1) ? 65536u : 0u;
    // issue next K-tile into the dead buffer; counted vmcnt leaves the 8 new
    // loads in flight across the barrier (they get a whole tile to land).
    if (t + 1 < NTK) {
      _Float16* nS = S + ((t + 1) & 1) * 32768;
      int kt = (t + 1) << 6;
#pragma unroll
      for (int o = 0; o < 4; ++o) {
        gl_lds16(aA + kt + (long)(o * 8) * K, nS + (wave * 32 + o * 8) * 64);
        gl_lds16(aB + kt + (long)(o * 8) * K, nS + 16384 + (wave * 32 + o * 8) * 64);
      }
      __builtin_amdgcn_sched_barrier(0);
      asm volatile("s_waitcnt vmcnt(8)" ::: "memory");
    } else {
      __builtin_amdgcn_sched_barrier(0);
      asm volatile("s_waitcnt vmcnt(0)" ::: "memory");
    }
    __builtin_amdgcn_sched_barrier(0);
    __builtin_amdgcn_s_barrier();   // current buffer fully staged (all waves)
    __builtin_amdgcn_sched_barrier(0);

    uint32_t a0 = db + aoff + x0, a1 = db + aoff + x1;
    uint32_t b0 = db + boff + x0, b1 = db + boff + x1;
    half8 aF[4][2], aG[4][2], bF0[2][2], bF1[2][2];
    // A-half 0 (8 reads) + B-quarter 0 (4 reads)
    aF[0][0] = dsr<0>(a0);     aF[0][1] = dsr<0>(a1);
    aF[1][0] = dsr<2048>(a0);  aF[1][1] = dsr<2048>(a1);
    aF[2][0] = dsr<4096>(a0);  aF[2][1] = dsr<4096>(a1);
    aF[3][0] = dsr<6144>(a0);  aF[3][1] = dsr<6144>(a1);
    bF0[0][0] = dsr<0>(b0);    bF0[0][1] = dsr<0>(b1);
    bF0[1][0] = dsr<2048>(b0); bF0[1][1] = dsr<2048>(b1);
    LGK0();
    // issue B-quarter 1 (serviced under Q00's MFMA)
    bF1[0][0] = dsr<4096>(b0); bF1[0][1] = dsr<4096>(b1);
    bF1[1][0] = dsr<6144>(b0); bF1[1][1] = dsr<6144>(b1);
    __builtin_amdgcn_s_setprio(1);
#pragma unroll
    for (int f = 0; f < 4; ++f)
#pragma unroll
      for (int j = 0; j < 2; ++j)
#pragma unroll
        for (int k2 = 0; k2 < 2; ++k2)
          acc[f][j] = __builtin_amdgcn_mfma_f32_16x16x32_f16(aF[f][k2], bF0[j][k2], acc[f][j], 0, 0, 0);
    __builtin_amdgcn_s_setprio(0);
    LGK0();
    // issue A-half 1 (serviced under Q01's MFMA)
    aG[0][0] = dsr<8192>(a0);  aG[0][1] = dsr<8192>(a1);
    aG[1][0] = dsr<10240>(a0); aG[1][1] = dsr<10240>(a1);
    aG[2][0] = dsr<12288>(a0); aG[2][1] = dsr<12288>(a1);
    aG[3][0] = dsr<14336>(a0); aG[3][1] = dsr<14336>(a1);
    __builtin_amdgcn_s_setprio(1);
#pragma unroll
    for (int f = 0; f < 4; ++f)
#pragma unroll
      for (int j = 0; j < 2; ++j)
#pragma unroll
        for (int k2 = 0; k2 < 2; ++k2)
          acc[f][2 + j] = __builtin_amdgcn_mfma_f32_16x16x32_f16(aF[f][k2], bF1[j][k2], acc[f][2 + j], 0, 0, 0);
    __builtin_amdgcn_s_setprio(0);
    LGK0();
    __builtin_amdgcn_s_barrier();   // all waves done reading this buffer ->
                                    // next iteration may overwrite it
    __builtin_amdgcn_sched_barrier(0);
    // Q10 + Q11: register-only; overlaps next tile's stage issue + vmcnt wait
    __builtin_amdgcn_s_setprio(1);
#pragma unroll
    for (int f = 0; f < 4; ++f)
#pragma unroll
      for (int j = 0; j < 2; ++j)
#pragma unroll
        for (int k2 = 0; k2 < 2; ++k2)
          acc[4 + f][j] = __builtin_amdgcn_mfma_f32_16x16x32_f16(aG[f][k2], bF0[j][k2], acc[4 + f][j], 0, 0, 0);
#pragma unroll
    for (int f = 0; f < 4; ++f)
#pragma unroll
      for (int j = 0; j < 2; ++j)
#pragma unroll
        for (int k2 = 0; k2 < 2; ++k2)
          acc[4 + f][2 + j] = __builtin_amdgcn_mfma_f32_16x16x32_f16(aG[f][k2], bF1[j][k2], acc[4 + f][2 + j], 0, 0, 0);
    __builtin_amdgcn_s_setprio(0);
  }
#pragma unroll
  for (int fj = 0; fj < 4; ++fj) {
    int n = bn0 + wc * 64 + fj * 16 + ll;
    float bj = bias[n];
#pragma unroll
    for (int fi = 0; fi < 8; ++fi) {
#pragma unroll
      for (int r = 0; r < 4; ++r) {
        long m = bm0 + wr * 128 + fi * 16 + quad * 4 + r;
        float v = acc[fi][fj][r] + bj;
        if (relu) v = fmaxf(v, 0.f);
        C[m * (long)ldC + n] = (_Float16)v;
      }
    }
  }
}

// ---------------- MFMA fused attention (V prefetched into registers)
__global__ __launch_bounds__(256) void attn_h(
    const _Float16* __restrict__ Qp, int qs,
    const _Float16* __restrict__ Kp, const _Float16* __restrict__ Vp, int ks,
    _Float16* __restrict__ Op, int mode_ca, int l0, int rb0)
{
  __shared__ _Float16 KV[128 * 72];
  __shared__ _Float16 Ps[128 * 136];
  int tid = threadIdx.x;
  int lane = tid & 63, wave = tid >> 6;
  int ll = lane & 15, quad = lane >> 4;
  int idx = blockIdx.x;
  int n = idx & 7;
  int rl = idx >> 3;
  long obase = (long)rl * 128 * 512 + n * 64;
  long qoff, koff;
  if (!mode_ca) {
    qoff = (long)rl * 128 * qs + n * 64;
    koff = (long)rl * 128 * ks + n * 64;
  } else {
    int g = rb0 + rl;
    int a = g >> 5;
    int qblk = l0 ? (g & 31) : rl;
    qoff = (long)qblk * 128 * qs + n * 64;
    koff = (long)a * 128 * ks + n * 64;
  }
  // stage K tile; prefetch Q and V from global before first barrier
#pragma unroll
  for (int it = 0; it < 4; ++it) {
    int e = tid + it * 256;
    int r = e >> 3, c = (e & 7) * 8;
    *(half8*)&KV[r * 72 + c] = *(const half8*)&Kp[koff + (long)r * ks + c];
  }
  half8 aQ[2][2];
#pragma unroll
  for (int i = 0; i < 2; ++i)
#pragma unroll
    for (int k2 = 0; k2 < 2; ++k2)
      aQ[i][k2] = *(const half8*)&Qp[qoff + (long)(wave * 32 + i * 16 + ll) * qs
                                     + quad * 8 + k2 * 32];
  half8 vreg[4];
#pragma unroll
  for (int it = 0; it < 4; ++it) {
    int e = tid + it * 256;
    int vr = e >> 3, c = (e & 7) * 8;
    vreg[it] = *(const half8*)&Vp[koff + (long)vr * ks + c];
  }
  __syncthreads();
  floatx4 accS[2][8];
#pragma unroll
  for (int i = 0; i < 2; ++i)
#pragma unroll
    for (int j = 0; j < 8; ++j) accS[i][j] = (floatx4){0.f, 0.f, 0.f, 0.f};
#pragma unroll
  for (int k2 = 0; k2 < 2; ++k2) {
#pragma unroll
    for (int j = 0; j < 8; ++j) {
      half8 bK = *(const half8*)&KV[(j * 16 + ll) * 72 + quad * 8 + k2 * 32];
      accS[0][j] = __builtin_amdgcn_mfma_f32_16x16x32_f16(aQ[0][k2], bK, accS[0][j], 0, 0, 0);
      accS[1][j] = __builtin_amdgcn_mfma_f32_16x16x32_f16(aQ[1][k2], bK, accS[1][j], 0, 0, 0);
    }
  }
  float rinv[2][4];
#pragma unroll
  for (int i = 0; i < 2; ++i) {
#pragma unroll
    for (int r = 0; r < 4; ++r) {
      float mx = -1e30f;
#pragma unroll
      for (int j = 0; j < 8; ++j) {
        accS[i][j][r] *= 0.125f;
        mx = fmaxf(mx, accS[i][j][r]);
      }
#pragma unroll
      for (int off = 1; off < 16; off <<= 1) mx = fmaxf(mx, __shfl_xor(mx, off));
      float s = 0.f;
#pragma unroll
      for (int j = 0; j < 8; ++j) {
        float e = __expf(accS[i][j][r] - mx);
        accS[i][j][r] = e;
        s += e;
      }
#pragma unroll
      for (int off = 1; off < 16; off <<= 1) s += __shfl_xor(s, off);
      rinv[i][r] = 1.f / s;
      int prow = wave * 32 + i * 16 + quad * 4 + r;
#pragma unroll
      for (int j = 0; j < 8; ++j)
        Ps[prow * 136 + j * 16 + ll] = (_Float16)accS[i][j][r];
    }
  }
  __syncthreads();   // K reads done; Ps visible
  // write prefetched V transposed: Vt[h][seq] at KV[h*132 + seq]
#pragma unroll
  for (int it = 0; it < 4; ++it) {
    int e = tid + it * 256;
    int vr = e >> 3, c = (e & 7) * 8;
#pragma unroll
    for (int j = 0; j < 8; ++j) KV[(c + j) * 132 + vr] = vreg[it][j];
  }
  __syncthreads();
  floatx4 accO[2][4];
#pragma unroll
  for (int i = 0; i < 2; ++i)
#pragma unroll
    for (int j = 0; j < 4; ++j) accO[i][j] = (floatx4){0.f, 0.f, 0.f, 0.f};
#pragma unroll
  for (int k4 = 0; k4 < 4; ++k4) {
    half8 aP[2];
#pragma unroll
    for (int i = 0; i < 2; ++i)
      aP[i] = *(const half8*)&Ps[(wave * 32 + i * 16 + ll) * 136 + quad * 8 + k4 * 32];
#pragma unroll
    for (int jh = 0; jh < 4; ++jh) {
      int vb = (jh * 16 + ll) * 132 + quad * 8 + k4 * 32;
      half4 v0 = *(const half4*)&KV[vb];
      half4 v1 = *(const half4*)&KV[vb + 4];
      half8 bV = __builtin_shufflevector(v0, v1, 0, 1, 2, 3, 4, 5, 6, 7);
      accO[0][jh] = __builtin_amdgcn_mfma_f32_16x16x32_f16(aP[0], bV, accO[0][jh], 0, 0, 0);
      accO[1][jh] = __builtin_amdgcn_mfma_f32_16x16x32_f16(aP[1], bV, accO[1][jh], 0, 0, 0);
    }
  }
#pragma unroll
  for (int i = 0; i < 2; ++i)
#pragma unroll
    for (int jh = 0; jh < 4; ++jh)
#pragma unroll
      for (int r = 0; r < 4; ++r) {
        int m = wave * 32 + i * 16 + quad * 4 + r;
        Op[obase + (long)m * 512 + jh * 16 + ll] = (_Float16)(accO[i][jh][r] * rinv[i][r]);
      }
}

// ---------------- Residual + LayerNorm (rows of 512, fp32 math). One wave per row.
__global__ __launch_bounds__(256) void ln_h(
    const void* __restrict__ xin, int xf32, const _Float16* __restrict__ add,
    _Float16* __restrict__ out, const float* __restrict__ g,
    const float* __restrict__ bt, long row0, int bmask)
{
  int rl = blockIdx.x * 4 + (threadIdx.x >> 6);
  long row = row0 + rl;
  int lane = threadIdx.x & 63;
  long xr = (row & (long)bmask) * 512 + lane * 8;
  float v[8];
  if (xf32) {
    float4 a0 = *(const float4*)((const float*)xin + xr);
    float4 a1 = *(const float4*)((const float*)xin + xr + 4);
    v[0] = a0.x; v[1] = a0.y; v[2] = a0.z; v[3] = a0.w;
    v[4] = a1.x; v[5] = a1.y; v[6] = a1.z; v[7] = a1.w;
  } else {
    half8 h = *(const half8*)((const _Float16*)xin + xr);
#pragma unroll
    for (int i = 0; i < 8; ++i) v[i] = (float)h[i];
  }
  if (add) {
    half8 a = *(const half8*)&add[(long)rl * 512 + lane * 8];
#pragma unroll
    for (int i = 0; i < 8; ++i) v[i] += (float)a[i];
  }
  float s = 0.f, sq = 0.f;
#pragma unroll
  for (int i = 0; i < 8; ++i) { s += v[i]; sq += v[i] * v[i]; }
#pragma unroll
  for (int off = 1; off < 64; off <<= 1) {
    s += __shfl_xor(s, off);
    sq += __shfl_xor(sq, off);
  }
  float mean = s * (1.f / 512.f);
  float var = sq * (1.f / 512.f) - mean * mean;
  float rst = rsqrtf(var + 1e-6f);
  int c = lane * 8;
  float4 g0 = *(const float4*)&g[c], g1 = *(const float4*)&g[c + 4];
  float4 b0 = *(const float4*)&bt[c], b1 = *(const float4*)&bt[c + 4];
  float gg[8] = {g0.x, g0.y, g0.z, g0.w, g1.x, g1.y, g1.z, g1.w};
  float bb[8] = {b0.x, b0.y, b0.z, b0.w, b1.x, b1.y, b1.z, b1.w};
  half8 o;
#pragma unroll
  for (int i = 0; i < 8; ++i) o[i] = (_Float16)((v[i] - mean) * rst * gg[i] + bb[i]);
  *(half8*)&out[row * 512 + c] = o;
}

// ---------------- batched 512x512 transpose-convert (12 weights in one launch)
__global__ __launch_bounds__(256) void tconv512(
    const float* __restrict__ w0, const float* __restrict__ w1,
    const float* __restrict__ w2, const float* __restrict__ w3,
    const float* __restrict__ w4, const float* __restrict__ w5,
    _Float16* __restrict__ Wh)
{
  __shared__ float T[64][65];
  int z = blockIdx.z;
  int t = z >> 1, l = z & 1;
  const float* src;
  long off;
  switch (t) {
    case 0: src = w0; off = 0; break;
    case 1: src = w1; off = 262144; break;
    case 2: src = w2; off = 524288; break;
    case 3: src = w3; off = 1048576; break;
    case 4: src = w4; off = 1310720; break;
    default: src = w5; off = 1572864; break;
  }
  src += (long)l * 262144;
  _Float16* out = Wh + (long)l * 4194304 + off;
  int tx = threadIdx.x & 63, tg = threadIdx.x >> 6;
  int r0 = blockIdx.y * 64, c0 = blockIdx.x * 64;
#pragma unroll
  for (int i = 0; i < 16; ++i)
    T[tg + 4 * i][tx] = src[(long)(r0 + tg + 4 * i) * 512 + c0 + tx];
  __syncthreads();
#pragma unroll
  for (int i = 0; i < 16; ++i)
    out[(long)(c0 + tg + 4 * i) * 512 + r0 + tx] = (_Float16)T[tx][tg + 4 * i];
}

// ---------------- layered transpose-convert for FFN weights
__global__ __launch_bounds__(256) void tconvL(const float* __restrict__ in,
                                              _Float16* __restrict__ out, int Rr, int Cc,
                                              long ils, long ols)
{
  __shared__ float T[64][65];
  in += (long)blockIdx.z * ils;
  out += (long)blockIdx.z * ols;
  int tx = threadIdx.x & 63, tg = threadIdx.x >> 6;
  int r0 = blockIdx.y * 64, c0 = blockIdx.x * 64;
#pragma unroll
  for (int i = 0; i < 16; ++i)
    T[tg + 4 * i][tx] = in[(long)(r0 + tg + 4 * i) * Cc + c0 + tx];
  __syncthreads();
#pragma unroll
  for (int i = 0; i < 16; ++i)
    out[(long)(c0 + tg + 4 * i) * Rr + r0 + tx] = (_Float16)T[tx][tg + 4 * i];
}

// ---------------- batched wo conversion
__global__ void woconvB(const float* __restrict__ sa_wo, const float* __restrict__ ca_wo,
                        _Float16* __restrict__ Wh)
{
  int z = blockIdx.y;
  int s = z >> 1, l = z & 1;
  const float* wo = (s ? ca_wo : sa_wo) + (long)l * 262144;
  _Float16* out = Wh + (long)l * 4194304 + (s ? 1835008 : 786432);
  int o = blockIdx.x * 256 + threadIdx.x;  // 262144
  int d = o >> 9;
  int nh = o & 511;
  int n = nh >> 6, h = nh & 63;
  out[o] = (_Float16)wo[((long)(n << 9) + d) * 64 + h];
}

// ---------------- pack all biases in one launch
__global__ void packbias(const float* __restrict__ sa_bq, const float* __restrict__ sa_bk,
                         const float* __restrict__ sa_bv, const float* __restrict__ ca_bk,
                         const float* __restrict__ ca_bv, float* __restrict__ Bqkv,
                         float* __restrict__ Bkv)
{
  int i = blockIdx.x * 256 + threadIdx.x;
  if (i >= 5120) return;
  int reg = i >> 9, idx = i & 511;
  int l = reg / 5, r = reg % 5;
  int lo = l * 512;
  switch (r) {
    case 0: Bqkv[l * 1536 + idx] = sa_bq[lo + idx]; break;
    case 1: Bqkv[l * 1536 + 512 + idx] = sa_bk[lo + idx]; break;
    case 2: Bqkv[l * 1536 + 1024 + idx] = sa_bv[lo + idx]; break;
    case 3: Bkv[l * 1024 + idx] = ca_bk[lo + idx]; break;
    default: Bkv[l * 1024 + 512 + idx] = ca_bv[lo + idx]; break;
  }
}

// ---------------- fused fp32->fp16 for c and q
__global__ void f2h2(const float* __restrict__ a, _Float16* __restrict__ oa, long na,
                     const float* __restrict__ bsrc, _Float16* __restrict__ ob, long nb)
{
  long i = blockIdx.x * 256L + threadIdx.x;
  if (i < na) oa[i] = (_Float16)a[i];
  else if (i < na + nb) ob[i - na] = (_Float16)bsrc[i - na];
}

// ---------------- fused pool(q fp32) + feature + normalize -> QN (8 x 256)
__global__ void featq_pool(const float* __restrict__ q, const float* __restrict__ W,
                           const float* __restrict__ bias, float* __restrict__ QN)
{
  __shared__ float sh[512];
  __shared__ float red[256];
  int a = blockIdx.x;
  int f = threadIdx.x;
  for (int dd = f; dd < 512; dd += 256) {
    const float* base = q + (long)a * 65536 + dd;
    float s = 0.f;
    for (int t = 1; t < 128; ++t) s += base[t * 512];
    sh[dd] = s * (1.f / 127.f);
  }
  __syncthreads();
  float acc = bias[f];
  for (int d = 0; d < 512; ++d) acc += sh[d] * W[d * 256 + f];
  red[f] = acc * acc;
  __syncthreads();
  for (int s = 128; s > 0; s >>= 1) {
    if (f < s) red[f] += red[f + s];
    __syncthreads();
  }
  float rn = rsqrtf(fmaxf(red[0], 1e-12f));
  QN[a * 256 + f] = acc * rn;
}

// ---------------- fused pool(X fp16) + feature + normalize + dot(QN) -> out (256)
__global__ void featc_pool(const _Float16* __restrict__ X, const float* __restrict__ W,
                           const float* __restrict__ bias, const float* __restrict__ QN,
                           float* __restrict__ out)
{
  __shared__ float sh[512];
  __shared__ float red[256];
  int ab = blockIdx.x;
  int f = threadIdx.x;
  for (int dd = f; dd < 512; dd += 256) {
    const _Float16* base = X + (long)ab * 65536 + dd;
    float s = 0.f;
    for (int t = 1; t < 128; ++t) s += (float)base[t * 512];
    sh[dd] = s * (1.f / 127.f);
  }
  __syncthreads();
  float acc = bias[f];
  for (int d = 0; d < 512; ++d) acc += sh[d] * W[d * 256 + f];
  red[f] = acc * acc;
  __syncthreads();
  for (int s = 128; s > 0; s >>= 1) {
    if (f < s) red[f] += red[f + s];
    __syncthreads();
  }
  float rn = rsqrtf(fmaxf(red[0], 1e-12f));
  float v = acc * rn * QN[(ab >> 5) * 256 + f];
  __syncthreads();
  red[f] = v;
  __syncthreads();
  for (int s = 128; s > 0; s >>= 1) {
    if (f < s) red[f] += red[f + s];
    __syncthreads();
  }
  if (f == 0) out[ab] = red[0];
}

extern "C" void kernel_launch(void* const* d_in, const int* in_sizes, int n_in,
                              void* d_out, int out_size, void* d_ws, size_t ws_size,
                              hipStream_t stream)
{
  (void)in_sizes; (void)n_in; (void)out_size;
  const float* c_in  = (const float*)d_in[0];
  const float* q_in  = (const float*)d_in[1];
  const float* sa_wq = (const float*)d_in[2];
  const float* sa_bq = (const float*)d_in[3];
  const float* sa_wk = (const float*)d_in[4];
  const float* sa_bk = (const float*)d_in[5];
  const float* sa_wv = (const float*)d_in[6];
  const float* sa_bv = (const float*)d_in[7];
  const float* sa_wo = (const float*)d_in[8];
  const float* sa_bo = (const float*)d_in[9];
  const float* ca_wq = (const float*)d_in[10];
  const float* ca_bq = (const float*)d_in[11];
  const float* ca_wk = (const float*)d_in[12];
  const float* ca_bk = (const float*)d_in[13];
  const float* ca_wv = (const float*)d_in[14];
  const float* ca_bv = (const float*)d_in[15];
  const float* ca_wo = (const float*)d_in[16];
  const float* ca_bo = (const float*)d_in[17];
  const float* ln1_g = (const float*)d_in[18];
  const float* ln1_b = (const float*)d_in[19];
  const float* ln2_g = (const float*)d_in[20];
  const float* ln2_b = (const float*)d_in[21];
  const float* ln3_g = (const float*)d_in[22];
  const float* ln3_b = (const float*)d_in[23];
  const float* ffn_w1 = (const float*)d_in[24];
  const float* ffn_b1 = (const float*)d_in[25];
  const float* ffn_w2 = (const float*)d_in[26];
  const float* ffn_b2 = (const float*)d_in[27];
  const float* lnf_g  = (const float*)d_in[28];
  const float* lnf_b  = (const float*)d_in[29];
  const float* feat_wq = (const float*)d_in[30];
  const float* feat_bq = (const float*)d_in[31];
  const float* feat_wc = (const float*)d_in[32];
  const float* feat_bc = (const float*)d_in[33];

  // ---- workspace layout
  char* p = (char*)d_ws;
  _Float16* Xh  = (_Float16*)p;  p += 33554432;  // 32768 x 512 fp16 residual stream
  _Float16* Xsh = (_Float16*)p;  p += 4194304;   //  4096 x 512 fp16 (layer-0 x)
  _Float16* Wh  = (_Float16*)p;  p += 16777216;  // fp16 weight arena (2 layers)
  _Float16* qh  = (_Float16*)p;  p += 1048576;   //  1024 x 512 fp16
  _Float16* KV0 = (_Float16*)p;  p += 2097152;   //  1024 x 1024 fp16 (K|V)
  float*    Bqkv = (float*)p;    p += 12288;
  float*    Bkv  = (float*)p;    p += 8192;
  float*    QN  = (float*)p;     p += 8192;
  const size_t fixed_b = (size_t)(p - (char*)d_ws);
  long R = 4096;
  if (ws_size >= fixed_b + 5120UL * 32768) R = 32768;
  else if (ws_size >= fixed_b + 5120UL * 16384) R = 16384;
  else if (ws_size >= fixed_b + 5120UL * 8192) R = 8192;
  _Float16* QKVc = (_Float16*)p; p += R * 3072;  // [R][1536]
  _Float16* Oc   = (_Float16*)p; p += R * 1024;  // [R][512]
  _Float16* Ac   = (_Float16*)p;                 // [R][512]
  _Float16* Hb = QKVc;            // FFN hidden [R][2048] spans QKVc+Oc (contiguous)
  const int MTR = (int)(R / 256);

  // ---- prep (6 launches)
  f2h2<<<10240, 256, 0, stream>>>(c_in, Xsh, 2097152, q_in, qh, 524288);
  tconv512<<<dim3(8, 8, 12), 256, 0, stream>>>(sa_wq, sa_wk, sa_wv, ca_wq, ca_wk, ca_wv, Wh);
  woconvB<<<dim3(1024, 4), 256, 0, stream>>>(sa_wo, ca_wo, Wh);
  tconvL<<<dim3(32, 8, 2), 256, 0, stream>>>(ffn_w1, Wh + 2097152, 512, 2048, 1048576, 4194304);
  tconvL<<<dim3(8, 32, 2), 256, 0, stream>>>(ffn_w2, Wh + 3145728, 2048, 512, 1048576, 4194304);
  packbias<<<20, 256, 0, stream>>>(sa_bq, sa_bk, sa_bv, ca_bk, ca_bv, Bqkv, Bkv);

  // =================== layer 0 (x rows = 4096) ===================
  {
    _Float16* Wl = Wh;
    gemm_h<<<dim3(12, 32), 256, 0, stream>>>(Xsh, Wl + 0, Bqkv, QKVc, 4096, 1536, 512, 1536, 0);
    attn_h<<<256, 256, 0, stream>>>(QKVc, 1536, QKVc + 512, QKVc + 1024, 1536, Oc, 0, 0, 0);
    gemm_h<<<dim3(4, 32), 256, 0, stream>>>(Oc, Wl + 786432, sa_bo, Ac, 4096, 512, 512, 512, 0);
    ln_h<<<1024, 256, 0, stream>>>(c_in, 1, Ac, Xsh, ln1_g, ln1_b, 0, 0x7FFFFFFF);
    gemm_h<<<dim3(4, 32), 256, 0, stream>>>(Xsh, Wl + 1048576, ca_bq, QKVc, 4096, 512, 512, 1536, 0);
    gemm_h<<<dim3(8, 8), 256, 0, stream>>>(qh, Wl + 1310720, Bkv, KV0, 1024, 1024, 512, 1024, 0);
    for (long c = 0; c < 32768; c += R) {
      attn_h<<<(R / 128) * 8, 256, 0, stream>>>(QKVc, 1536, KV0, KV0 + 512, 1024, Oc,
                                                1, 1, (int)(c / 128));
      gemm8<<<MTR * 2, 512, 0, stream>>>(Oc, Wl + 1835008, ca_bo, Ac, MTR, 2, 512, 512, 0);
      ln_h<<<R / 4, 256, 0, stream>>>(Xsh, 0, Ac, Xh, ln2_g, ln2_b, c, 4095);
      gemm8<<<MTR * 8, 512, 0, stream>>>(Xh + c * 512, Wl + 2097152,
                                         ffn_b1, Hb, MTR, 8, 512, 2048, 1);
      gemm8<<<MTR * 2, 512, 0, stream>>>(Hb, Wl + 3145728, ffn_b2, Ac, MTR, 2, 2048, 512, 0);
      ln_h<<<R / 4, 256, 0, stream>>>(Xh, 0, Ac, Xh, ln3_g, ln3_b, c, 0x7FFFFFFF);
    }
  }
  // =================== layer 1 (x rows = 32768) ===================
  {
    _Float16* Wl = Wh + 4194304;
    gemm_h<<<dim3(8, 8), 256, 0, stream>>>(qh, Wl + 1310720, Bkv + 1024, KV0, 1024, 1024, 512, 1024, 0);
    for (long c = 0; c < 32768; c += R) {
      _Float16* Xhc = Xh + c * 512;
      gemm8<<<MTR * 6, 512, 0, stream>>>(Xhc, Wl + 0, Bqkv + 1536, QKVc, MTR, 6, 512, 1536, 0);
      attn_h<<<(R / 128) * 8, 256, 0, stream>>>(QKVc, 1536, QKVc + 512, QKVc + 1024, 1536,
                                                Oc, 0, 0, 0);
      gemm8<<<MTR * 2, 512, 0, stream>>>(Oc, Wl + 786432, sa_bo + 512, Ac, MTR, 2, 512, 512, 0);
      ln_h<<<R / 4, 256, 0, stream>>>(Xh, 0, Ac, Xh, ln1_g + 512, ln1_b + 512, c, 0x7FFFFFFF);
      gemm8<<<MTR * 2, 512, 0, stream>>>(Xhc, Wl + 1048576, ca_bq + 512, QKVc, MTR, 2, 512, 1536, 0);
      attn_h<<<(R / 128) * 8, 256, 0, stream>>>(QKVc, 1536, KV0, KV0 + 512, 1024, Oc,
                                                1, 0, (int)(c / 128));
      gemm8<<<MTR * 2, 512, 0, stream>>>(Oc, Wl + 1835008, ca_bo + 512, Ac, MTR, 2, 512, 512, 0);
      ln_h<<<R / 4, 256, 0, stream>>>(Xh, 0, Ac, Xh, ln2_g + 512, ln2_b + 512, c, 0x7FFFFFFF);
      gemm8<<<MTR * 8, 512, 0, stream>>>(Xh + c * 512, Wl + 2097152,
                                         ffn_b1 + 2048, Hb, MTR, 8, 512, 2048, 1);
      gemm8<<<MTR * 2, 512, 0, stream>>>(Hb, Wl + 3145728, ffn_b2 + 512, Ac, MTR, 2, 2048, 512, 0);
      ln_h<<<R / 4, 256, 0, stream>>>(Xh, 0, Ac, Xh, ln3_g + 512, ln3_b + 512, c, 0x7FFFFFFF);
    }
  }
  // =================== final LN + fused pool/features/cosine ===================
  ln_h<<<8192, 256, 0, stream>>>(Xh, 0, nullptr, Xh, lnf_g, lnf_b, 0, 0x7FFFFFFF);
  featq_pool<<<8, 256, 0, stream>>>(q_in, feat_wq, feat_bq, QN);
  featc_pool<<<256, 256, 0, stream>>>(Xh, feat_wc, feat_bc, QN, (float*)d_out);
}

// Round 3
// 987.611 us; speedup vs baseline: 1.0680x; 1.0139x over previous
//
#include <hip/hip_runtime.h>

using half4  = __attribute__((ext_vector_type(4))) _Float16;
using half8  = __attribute__((ext_vector_type(8))) _Float16;
using floatx4 = __attribute__((ext_vector_type(4))) float;

__device__ __forceinline__ void gl_lds16(const _Float16* g, _Float16* l)
{
  __builtin_amdgcn_global_load_lds(
      (const __attribute__((address_space(1))) void*)g,
      (__attribute__((address_space(3))) void*)l, 16, 0, 0);
}

__device__ __forceinline__ uint32_t lds_u32(const _Float16* p)
{
  return (uint32_t)(uintptr_t)(const __attribute__((address_space(3))) _Float16*)p;
}

// inline-asm LDS read: opaque to the compiler's waitcnt insertion (it would
// otherwise emit vmcnt(0) before LDS reads that might alias pending
// global_load_lds destinations, killing the counted-vmcnt pipeline).
template<int IMM>
__device__ __forceinline__ half8 dsr(uint32_t addr)
{
  half8 r;
  asm volatile("ds_read_b128 %0, %1 offset:%2" : "=v"(r) : "v"(addr), "i"(IMM));
  return r;
}

// rule #18: any asm waitcnt must be followed by sched_barrier(0)
#define WAITLGKM(N) do { asm volatile("s_waitcnt lgkmcnt(" #N ")" ::: "memory"); \
                         __builtin_amdgcn_sched_barrier(0); } while (0)

// ---------------- MFMA fp16 GEMM (128x128 tile, BK=32, seg-XOR swizzled)
__global__ __launch_bounds__(256) void gemm_h(
    const _Float16* __restrict__ A, const _Float16* __restrict__ Bt,
    const float* __restrict__ bias, _Float16* __restrict__ C,
    int M, int N, int K, int ldC, int relu)
{
  __shared__ _Float16 As[128 * 32];
  __shared__ _Float16 Bs[128 * 32];
  int tid = threadIdx.x;
  int lane = tid & 63, wave = tid >> 6;
  long bm0 = (long)blockIdx.y * 128;
  int bn0 = blockIdx.x * 128;
  int wm = (wave & 1) * 64, wn = (wave >> 1) * 64;
  int srow = wave * 16 + (lane >> 2);
  int scol = (((lane & 3) ^ ((lane >> 3) & 3)) * 8);
  const _Float16* aA0 = A + (bm0 + srow) * (long)K + scol;
  const _Float16* aA1 = aA0 + 64 * (long)K;
  const _Float16* aB0 = Bt + (bn0 + srow) * (long)K + scol;
  const _Float16* aB1 = aB0 + 64 * (long)K;
  _Float16* lA0 = As + wave * 512;
  _Float16* lA1 = As + 2048 + wave * 512;
  _Float16* lB0 = Bs + wave * 512;
  _Float16* lB1 = Bs + 2048 + wave * 512;
  int mrow = lane & 15, quad = lane >> 4;
  int cofs = (quad ^ ((mrow >> 1) & 3)) * 8;
  floatx4 acc[4][4];
#pragma unroll
  for (int i = 0; i < 4; ++i)
#pragma unroll
    for (int j = 0; j < 4; ++j) acc[i][j] = (floatx4){0.f, 0.f, 0.f, 0.f};

  for (int kt = 0; kt < K; kt += 32) {
    __syncthreads();
    gl_lds16(aA0 + kt, lA0);
    gl_lds16(aA1 + kt, lA1);
    gl_lds16(aB0 + kt, lB0);
    gl_lds16(aB1 + kt, lB1);
    __syncthreads();
    half8 af[4], bf[4];
#pragma unroll
    for (int i = 0; i < 4; ++i)
      af[i] = *(const half8*)&As[(wm + 16 * i + mrow) * 32 + cofs];
#pragma unroll
    for (int j = 0; j < 4; ++j)
      bf[j] = *(const half8*)&Bs[(wn + 16 * j + mrow) * 32 + cofs];
#pragma unroll
    for (int i = 0; i < 4; ++i)
#pragma unroll
      for (int j = 0; j < 4; ++j)
        acc[i][j] = __builtin_amdgcn_mfma_f32_16x16x32_f16(af[i], bf[j], acc[i][j], 0, 0, 0);
  }
#pragma unroll
  for (int j = 0; j < 4; ++j) {
    int n = bn0 + wn + 16 * j + mrow;
    float bj = bias[n];
#pragma unroll
    for (int i = 0; i < 4; ++i) {
#pragma unroll
      for (int r = 0; r < 4; ++r) {
        long m = bm0 + wm + 16 * i + quad * 4 + r;
        float v = acc[i][j][r] + bj;
        if (relu) v = fmaxf(v, 0.f);
        C[m * (long)ldC + n] = (_Float16)v;
      }
    }
  }
}

// ---------------- MFMA fp16 GEMM (256x256 tile, BK=64, 8-wave, dbuf LDS,
//  4-phase pipeline: one-phase read-ahead, counted lgkmcnt, k2-split phases,
//  1 barrier + 1 vmcnt per K-tile)
__global__ __launch_bounds__(512, 2) void gemm8(
    const _Float16* __restrict__ A, const _Float16* __restrict__ Bt,
    const float* __restrict__ bias, _Float16* __restrict__ C,
    int MT, int NT, int K, int ldC, int relu)
{
  __shared__ _Float16 S[65536];   // 2 x (A 256x64 + B 256x64) fp16 = 128 KB
  int tid = threadIdx.x;
  int lane = tid & 63, wave = tid >> 6;
  int L = blockIdx.x;
  int xcd = L & 7, seq = L >> 3;
  int band = MT >> 3;                 // MT always a multiple of 8 here
  int mt = xcd * band + seq / NT;
  int nt = seq - (seq / NT) * NT;
  long bm0 = (long)mt * 256;
  int bn0 = nt * 256;
  int r8 = lane >> 3, s8 = lane & 7;
  int scol = (s8 ^ r8) * 8;           // pre-swizzled global source seg
  const _Float16* aA = A + (bm0 + wave * 32 + r8) * (long)K + scol;
  const _Float16* aB = Bt + (bn0 + wave * 32 + r8) * (long)K + scol;
  int wr = wave >> 2, wc = wave & 3;  // 2 x 4 wave grid, per-wave C = 128 x 64
  int ll = lane & 15, quad = lane >> 4;
  int lw = ll & 7;
  // byte-unit LDS addresses for asm ds_read
  uint32_t aoff = lds_u32(S) + (uint32_t)(wr * 128 + ll) * 128u;
  uint32_t boff = lds_u32(S) + 32768u + (uint32_t)(wc * 64 + ll) * 128u;
  uint32_t x0 = (uint32_t)((quad ^ lw) * 16);          // k2 = 0 seg
  uint32_t x1 = (uint32_t)(((quad + 4) ^ lw) * 16);    // k2 = 1 seg
  floatx4 acc[8][4];
#pragma unroll
  for (int i = 0; i < 8; ++i)
#pragma unroll
    for (int j = 0; j < 4; ++j) acc[i][j] = (floatx4){0.f, 0.f, 0.f, 0.f};

  int NTK = K >> 6;
  // prologue: stage K-tile 0 into buffer 0, wait, publish
#pragma unroll
  for (int o = 0; o < 4; ++o) {
    gl_lds16(aA + (long)(o * 8) * K, S + (wave * 32 + o * 8) * 64);
    gl_lds16(aB + (long)(o * 8) * K, S + 16384 + (wave * 32 + o * 8) * 64);
  }
  asm volatile("s_waitcnt vmcnt(0)" ::: "memory");
  __builtin_amdgcn_sched_barrier(0);
  __builtin_amdgcn_s_barrier();

  for (int t = 0; t < NTK; ++t) {
    uint32_t db = (t & 1) ? 65536u : 0u;
    // issue next K-tile into the dead buffer; these loads stay in flight for
    // the entire current tile (~2.4k cycles >> HBM latency).
    __builtin_amdgcn_sched_barrier(0);
    if (t + 1 < NTK) {
      _Float16* nS = S + ((t + 1) & 1) * 32768;
      int kt = (t + 1) << 6;
#pragma unroll
      for (int o = 0; o < 4; ++o) {
        gl_lds16(aA + kt + (long)(o * 8) * K, nS + (wave * 32 + o * 8) * 64);
        gl_lds16(aB + kt + (long)(o * 8) * K, nS + 16384 + (wave * 32 + o * 8) * 64);
      }
    }
    __builtin_amdgcn_sched_barrier(0);
    uint32_t a0 = db + aoff + x0, a1 = db + aoff + x1;
    uint32_t b0 = db + boff + x0, b1 = db + boff + x1;
    half8 A0[4], A1[4], B0[4], B1[4];
    // P0 reads (fi 0-3, k2=0) + P1 reads (fi 0-3, k2=1): 16 in flight
    A0[0] = dsr<0>(a0);    A0[1] = dsr<2048>(a0);
    A0[2] = dsr<4096>(a0); A0[3] = dsr<6144>(a0);
    B0[0] = dsr<0>(b0);    B0[1] = dsr<2048>(b0);
    B0[2] = dsr<4096>(b0); B0[3] = dsr<6144>(b0);
    A1[0] = dsr<0>(a1);    A1[1] = dsr<2048>(a1);
    A1[2] = dsr<4096>(a1); A1[3] = dsr<6144>(a1);
    B1[0] = dsr<0>(b1);    B1[1] = dsr<2048>(b1);
    B1[2] = dsr<4096>(b1); B1[3] = dsr<6144>(b1);
    WAITLGKM(8);            // P0 operands ready; P1's 8 still in flight
    __builtin_amdgcn_s_setprio(1);
#pragma unroll
    for (int f = 0; f < 4; ++f)       // P0: 16 independent MFMAs (k2=0)
#pragma unroll
      for (int j = 0; j < 4; ++j)
        acc[f][j] = __builtin_amdgcn_mfma_f32_16x16x32_f16(A0[f], B0[j], acc[f][j], 0, 0, 0);
    __builtin_amdgcn_s_setprio(0);
    __builtin_amdgcn_sched_barrier(0);
    // P2 reads (fi 4-7, k2=0); A0 regs safe to reuse (LDS return latency >>
    // MFMA operand-read window)
    A0[0] = dsr<8192>(a0);  A0[1] = dsr<10240>(a0);
    A0[2] = dsr<12288>(a0); A0[3] = dsr<14336>(a0);
    WAITLGKM(4);            // P1 ready; P2's 4 in flight
    __builtin_amdgcn_s_setprio(1);
#pragma unroll
    for (int f = 0; f < 4; ++f)       // P1 (k2=1)
#pragma unroll
      for (int j = 0; j < 4; ++j)
        acc[f][j] = __builtin_amdgcn_mfma_f32_16x16x32_f16(A1[f], B1[j], acc[f][j], 0, 0, 0);
    __builtin_amdgcn_s_setprio(0);
    __builtin_amdgcn_sched_barrier(0);
    // P3 reads (fi 4-7, k2=1)
    A1[0] = dsr<8192>(a1);  A1[1] = dsr<10240>(a1);
    A1[2] = dsr<12288>(a1); A1[3] = dsr<14336>(a1);
    WAITLGKM(4);            // P2 ready; P3's 4 in flight
    __builtin_amdgcn_s_setprio(1);
#pragma unroll
    for (int f = 0; f < 4; ++f)       // P2: B0 reused from registers
#pragma unroll
      for (int j = 0; j < 4; ++j)
        acc[4 + f][j] = __builtin_amdgcn_mfma_f32_16x16x32_f16(A0[f], B0[j], acc[4 + f][j], 0, 0, 0);
    __builtin_amdgcn_s_setprio(0);
    WAITLGKM(0);            // P3 ready
    __builtin_amdgcn_s_setprio(1);
#pragma unroll
    for (int f = 0; f < 4; ++f)       // P3: B1 reused from registers
#pragma unroll
      for (int j = 0; j < 4; ++j)
        acc[4 + f][j] = __builtin_amdgcn_mfma_f32_16x16x32_f16(A1[f], B1[j], acc[4 + f][j], 0, 0, 0);
    __builtin_amdgcn_s_setprio(0);
    __builtin_amdgcn_sched_barrier(0);
    // next-tile loads landed (issued a whole tile ago); publish to all waves
    asm volatile("s_waitcnt vmcnt(0)" ::: "memory");
    __builtin_amdgcn_sched_barrier(0);
    __builtin_amdgcn_s_barrier();
  }
#pragma unroll
  for (int fj = 0; fj < 4; ++fj) {
    int n = bn0 + wc * 64 + fj * 16 + ll;
    float bj = bias[n];
#pragma unroll
    for (int fi = 0; fi < 8; ++fi) {
#pragma unroll
      for (int r = 0; r < 4; ++r) {
        long m = bm0 + wr * 128 + fi * 16 + quad * 4 + r;
        float v = acc[fi][fj][r] + bj;
        if (relu) v = fmaxf(v, 0.f);
        C[m * (long)ldC + n] = (_Float16)v;
      }
    }
  }
}

// ---------------- MFMA fused attention (V prefetched into registers)
__global__ __launch_bounds__(256) void attn_h(
    const _Float16* __restrict__ Qp, int qs,
    const _Float16* __restrict__ Kp, const _Float16* __restrict__ Vp, int ks,
    _Float16* __restrict__ Op, int mode_ca, int l0, int rb0)
{
  __shared__ _Float16 KV[128 * 72];
  __shared__ _Float16 Ps[128 * 136];
  int tid = threadIdx.x;
  int lane = tid & 63, wave = tid >> 6;
  int ll = lane & 15, quad = lane >> 4;
  int idx = blockIdx.x;
  int n = idx & 7;
  int rl = idx >> 3;
  long obase = (long)rl * 128 * 512 + n * 64;
  long qoff, koff;
  if (!mode_ca) {
    qoff = (long)rl * 128 * qs + n * 64;
    koff = (long)rl * 128 * ks + n * 64;
  } else {
    int g = rb0 + rl;
    int a = g >> 5;
    int qblk = l0 ? (g & 31) : rl;
    qoff = (long)qblk * 128 * qs + n * 64;
    koff = (long)a * 128 * ks + n * 64;
  }
  // stage K tile; prefetch Q and V from global before first barrier
#pragma unroll
  for (int it = 0; it < 4; ++it) {
    int e = tid + it * 256;
    int r = e >> 3, c = (e & 7) * 8;
    *(half8*)&KV[r * 72 + c] = *(const half8*)&Kp[koff + (long)r * ks + c];
  }
  half8 aQ[2][2];
#pragma unroll
  for (int i = 0; i < 2; ++i)
#pragma unroll
    for (int k2 = 0; k2 < 2; ++k2)
      aQ[i][k2] = *(const half8*)&Qp[qoff + (long)(wave * 32 + i * 16 + ll) * qs
                                     + quad * 8 + k2 * 32];
  half8 vreg[4];
#pragma unroll
  for (int it = 0; it < 4; ++it) {
    int e = tid + it * 256;
    int vr = e >> 3, c = (e & 7) * 8;
    vreg[it] = *(const half8*)&Vp[koff + (long)vr * ks + c];
  }
  __syncthreads();
  floatx4 accS[2][8];
#pragma unroll
  for (int i = 0; i < 2; ++i)
#pragma unroll
    for (int j = 0; j < 8; ++j) accS[i][j] = (floatx4){0.f, 0.f, 0.f, 0.f};
#pragma unroll
  for (int k2 = 0; k2 < 2; ++k2) {
#pragma unroll
    for (int j = 0; j < 8; ++j) {
      half8 bK = *(const half8*)&KV[(j * 16 + ll) * 72 + quad * 8 + k2 * 32];
      accS[0][j] = __builtin_amdgcn_mfma_f32_16x16x32_f16(aQ[0][k2], bK, accS[0][j], 0, 0, 0);
      accS[1][j] = __builtin_amdgcn_mfma_f32_16x16x32_f16(aQ[1][k2], bK, accS[1][j], 0, 0, 0);
    }
  }
  float rinv[2][4];
#pragma unroll
  for (int i = 0; i < 2; ++i) {
#pragma unroll
    for (int r = 0; r < 4; ++r) {
      float mx = -1e30f;
#pragma unroll
      for (int j = 0; j < 8; ++j) {
        accS[i][j][r] *= 0.125f;
        mx = fmaxf(mx, accS[i][j][r]);
      }
#pragma unroll
      for (int off = 1; off < 16; off <<= 1) mx = fmaxf(mx, __shfl_xor(mx, off));
      float s = 0.f;
#pragma unroll
      for (int j = 0; j < 8; ++j) {
        float e = __expf(accS[i][j][r] - mx);
        accS[i][j][r] = e;
        s += e;
      }
#pragma unroll
      for (int off = 1; off < 16; off <<= 1) s += __shfl_xor(s, off);
      rinv[i][r] = 1.f / s;
      int prow = wave * 32 + i * 16 + quad * 4 + r;
#pragma unroll
      for (int j = 0; j < 8; ++j)
        Ps[prow * 136 + j * 16 + ll] = (_Float16)accS[i][j][r];
    }
  }
  __syncthreads();   // K reads done; Ps visible
  // write prefetched V transposed: Vt[h][seq] at KV[h*132 + seq]
#pragma unroll
  for (int it = 0; it < 4; ++it) {
    int e = tid + it * 256;
    int vr = e >> 3, c = (e & 7) * 8;
#pragma unroll
    for (int j = 0; j < 8; ++j) KV[(c + j) * 132 + vr] = vreg[it][j];
  }
  __syncthreads();
  floatx4 accO[2][4];
#pragma unroll
  for (int i = 0; i < 2; ++i)
#pragma unroll
    for (int j = 0; j < 4; ++j) accO[i][j] = (floatx4){0.f, 0.f, 0.f, 0.f};
#pragma unroll
  for (int k4 = 0; k4 < 4; ++k4) {
    half8 aP[2];
#pragma unroll
    for (int i = 0; i < 2; ++i)
      aP[i] = *(const half8*)&Ps[(wave * 32 + i * 16 + ll) * 136 + quad * 8 + k4 * 32];
#pragma unroll
    for (int jh = 0; jh < 4; ++jh) {
      int vb = (jh * 16 + ll) * 132 + quad * 8 + k4 * 32;
      half4 v0 = *(const half4*)&KV[vb];
      half4 v1 = *(const half4*)&KV[vb + 4];
      half8 bV = __builtin_shufflevector(v0, v1, 0, 1, 2, 3, 4, 5, 6, 7);
      accO[0][jh] = __builtin_amdgcn_mfma_f32_16x16x32_f16(aP[0], bV, accO[0][jh], 0, 0, 0);
      accO[1][jh] = __builtin_amdgcn_mfma_f32_16x16x32_f16(aP[1], bV, accO[1][jh], 0, 0, 0);
    }
  }
#pragma unroll
  for (int i = 0; i < 2; ++i)
#pragma unroll
    for (int jh = 0; jh < 4; ++jh)
#pragma unroll
      for (int r = 0; r < 4; ++r) {
        int m = wave * 32 + i * 16 + quad * 4 + r;
        Op[obase + (long)m * 512 + jh * 16 + ll] = (_Float16)(accO[i][jh][r] * rinv[i][r]);
      }
}

// ---------------- Residual + LayerNorm (rows of 512, fp32 math). One wave per row.
__global__ __launch_bounds__(256) void ln_h(
    const void* __restrict__ xin, int xf32, const _Float16* __restrict__ add,
    _Float16* __restrict__ out, const float* __restrict__ g,
    const float* __restrict__ bt, long row0, int bmask)
{
  int rl = blockIdx.x * 4 + (threadIdx.x >> 6);
  long row = row0 + rl;
  int lane = threadIdx.x & 63;
  long xr = (row & (long)bmask) * 512 + lane * 8;
  float v[8];
  if (xf32) {
    float4 a0 = *(const float4*)((const float*)xin + xr);
    float4 a1 = *(const float4*)((const float*)xin + xr + 4);
    v[0] = a0.x; v[1] = a0.y; v[2] = a0.z; v[3] = a0.w;
    v[4] = a1.x; v[5] = a1.y; v[6] = a1.z; v[7] = a1.w;
  } else {
    half8 h = *(const half8*)((const _Float16*)xin + xr);
#pragma unroll
    for (int i = 0; i < 8; ++i) v[i] = (float)h[i];
  }
  if (add) {
    half8 a = *(const half8*)&add[(long)rl * 512 + lane * 8];
#pragma unroll
    for (int i = 0; i < 8; ++i) v[i] += (float)a[i];
  }
  float s = 0.f, sq = 0.f;
#pragma unroll
  for (int i = 0; i < 8; ++i) { s += v[i]; sq += v[i] * v[i]; }
#pragma unroll
  for (int off = 1; off < 64; off <<= 1) {
    s += __shfl_xor(s, off);
    sq += __shfl_xor(sq, off);
  }
  float mean = s * (1.f / 512.f);
  float var = sq * (1.f / 512.f) - mean * mean;
  float rst = rsqrtf(var + 1e-6f);
  int c = lane * 8;
  float4 g0 = *(const float4*)&g[c], g1 = *(const float4*)&g[c + 4];
  float4 b0 = *(const float4*)&bt[c], b1 = *(const float4*)&bt[c + 4];
  float gg[8] = {g0.x, g0.y, g0.z, g0.w, g1.x, g1.y, g1.z, g1.w};
  float bb[8] = {b0.x, b0.y, b0.z, b0.w, b1.x, b1.y, b1.z, b1.w};
  half8 o;
#pragma unroll
  for (int i = 0; i < 8; ++i) o[i] = (_Float16)((v[i] - mean) * rst * gg[i] + bb[i]);
  *(half8*)&out[row * 512 + c] = o;
}

// ---------------- batched 512x512 transpose-convert (12 weights in one launch)
__global__ __launch_bounds__(256) void tconv512(
    const float* __restrict__ w0, const float* __restrict__ w1,
    const float* __restrict__ w2, const float* __restrict__ w3,
    const float* __restrict__ w4, const float* __restrict__ w5,
    _Float16* __restrict__ Wh)
{
  __shared__ float T[64][65];
  int z = blockIdx.z;
  int t = z >> 1, l = z & 1;
  const float* src;
  long off;
  switch (t) {
    case 0: src = w0; off = 0; break;
    case 1: src = w1; off = 262144; break;
    case 2: src = w2; off = 524288; break;
    case 3: src = w3; off = 1048576; break;
    case 4: src = w4; off = 1310720; break;
    default: src = w5; off = 1572864; break;
  }
  src += (long)l * 262144;
  _Float16* out = Wh + (long)l * 4194304 + off;
  int tx = threadIdx.x & 63, tg = threadIdx.x >> 6;
  int r0 = blockIdx.y * 64, c0 = blockIdx.x * 64;
#pragma unroll
  for (int i = 0; i < 16; ++i)
    T[tg + 4 * i][tx] = src[(long)(r0 + tg + 4 * i) * 512 + c0 + tx];
  __syncthreads();
#pragma unroll
  for (int i = 0; i < 16; ++i)
    out[(long)(c0 + tg + 4 * i) * 512 + r0 + tx] = (_Float16)T[tx][tg + 4 * i];
}

// ---------------- layered transpose-convert for FFN weights
__global__ __launch_bounds__(256) void tconvL(const float* __restrict__ in,
                                              _Float16* __restrict__ out, int Rr, int Cc,
                                              long ils, long ols)
{
  __shared__ float T[64][65];
  in += (long)blockIdx.z * ils;
  out += (long)blockIdx.z * ols;
  int tx = threadIdx.x & 63, tg = threadIdx.x >> 6;
  int r0 = blockIdx.y * 64, c0 = blockIdx.x * 64;
#pragma unroll
  for (int i = 0; i < 16; ++i)
    T[tg + 4 * i][tx] = in[(long)(r0 + tg + 4 * i) * Cc + c0 + tx];
  __syncthreads();
#pragma unroll
  for (int i = 0; i < 16; ++i)
    out[(long)(c0 + tg + 4 * i) * Rr + r0 + tx] = (_Float16)T[tx][tg + 4 * i];
}

// ---------------- batched wo conversion
__global__ void woconvB(const float* __restrict__ sa_wo, const float* __restrict__ ca_wo,
                        _Float16* __restrict__ Wh)
{
  int z = blockIdx.y;
  int s = z >> 1, l = z & 1;
  const float* wo = (s ? ca_wo : sa_wo) + (long)l * 262144;
  _Float16* out = Wh + (long)l * 4194304 + (s ? 1835008 : 786432);
  int o = blockIdx.x * 256 + threadIdx.x;  // 262144
  int d = o >> 9;
  int nh = o & 511;
  int n = nh >> 6, h = nh & 63;
  out[o] = (_Float16)wo[((long)(n << 9) + d) * 64 + h];
}

// ---------------- pack all biases in one launch
__global__ void packbias(const float* __restrict__ sa_bq, const float* __restrict__ sa_bk,
                         const float* __restrict__ sa_bv, const float* __restrict__ ca_bk,
                         const float* __restrict__ ca_bv, float* __restrict__ Bqkv,
                         float* __restrict__ Bkv)
{
  int i = blockIdx.x * 256 + threadIdx.x;
  if (i >= 5120) return;
  int reg = i >> 9, idx = i & 511;
  int l = reg / 5, r = reg % 5;
  int lo = l * 512;
  switch (r) {
    case 0: Bqkv[l * 1536 + idx] = sa_bq[lo + idx]; break;
    case 1: Bqkv[l * 1536 + 512 + idx] = sa_bk[lo + idx]; break;
    case 2: Bqkv[l * 1536 + 1024 + idx] = sa_bv[lo + idx]; break;
    case 3: Bkv[l * 1024 + idx] = ca_bk[lo + idx]; break;
    default: Bkv[l * 1024 + 512 + idx] = ca_bv[lo + idx]; break;
  }
}

// ---------------- fused fp32->fp16 for c and q
__global__ void f2h2(const float* __restrict__ a, _Float16* __restrict__ oa, long na,
                     const float* __restrict__ bsrc, _Float16* __restrict__ ob, long nb)
{
  long i = blockIdx.x * 256L + threadIdx.x;
  if (i < na) oa[i] = (_Float16)a[i];
  else if (i < na + nb) ob[i - na] = (_Float16)bsrc[i - na];
}

// ---------------- fused pool(q fp32) + feature + normalize -> QN (8 x 256)
__global__ void featq_pool(const float* __restrict__ q, const float* __restrict__ W,
                           const float* __restrict__ bias, float* __restrict__ QN)
{
  __shared__ float sh[512];
  __shared__ float red[256];
  int a = blockIdx.x;
  int f = threadIdx.x;
  for (int dd = f; dd < 512; dd += 256) {
    const float* base = q + (long)a * 65536 + dd;
    float s = 0.f;
    for (int t = 1; t < 128; ++t) s += base[t * 512];
    sh[dd] = s * (1.f / 127.f);
  }
  __syncthreads();
  float acc = bias[f];
  for (int d = 0; d < 512; ++d) acc += sh[d] * W[d * 256 + f];
  red[f] = acc * acc;
  __syncthreads();
  for (int s = 128; s > 0; s >>= 1) {
    if (f < s) red[f] += red[f + s];
    __syncthreads();
  }
  float rn = rsqrtf(fmaxf(red[0], 1e-12f));
  QN[a * 256 + f] = acc * rn;
}

// ---------------- fused pool(X fp16) + feature + normalize + dot(QN) -> out (256)
__global__ void featc_pool(const _Float16* __restrict__ X, const float* __restrict__ W,
                           const float* __restrict__ bias, const float* __restrict__ QN,
                           float* __restrict__ out)
{
  __shared__ float sh[512];
  __shared__ float red[256];
  int ab = blockIdx.x;
  int f = threadIdx.x;
  for (int dd = f; dd < 512; dd += 256) {
    const _Float16* base = X + (long)ab * 65536 + dd;
    float s = 0.f;
    for (int t = 1; t < 128; ++t) s += (float)base[t * 512];
    sh[dd] = s * (1.f / 127.f);
  }
  __syncthreads();
  float acc = bias[f];
  for (int d = 0; d < 512; ++d) acc += sh[d] * W[d * 256 + f];
  red[f] = acc * acc;
  __syncthreads();
  for (int s = 128; s > 0; s >>= 1) {
    if (f < s) red[f] += red[f + s];
    __syncthreads();
  }
  float rn = rsqrtf(fmaxf(red[0], 1e-12f));
  float v = acc * rn * QN[(ab >> 5) * 256 + f];
  __syncthreads();
  red[f] = v;
  __syncthreads();
  for (int s = 128; s > 0; s >>= 1) {
    if (f < s) red[f] += red[f + s];
    __syncthreads();
  }
  if (f == 0) out[ab] = red[0];
}

extern "C" void kernel_launch(void* const* d_in, const int* in_sizes, int n_in,
                              void* d_out, int out_size, void* d_ws, size_t ws_size,
                              hipStream_t stream)
{
  (void)in_sizes; (void)n_in; (void)out_size;
  const float* c_in  = (const float*)d_in[0];
  const float* q_in  = (const float*)d_in[1];
  const float* sa_wq = (const float*)d_in[2];
  const float* sa_bq = (const float*)d_in[3];
  const float* sa_wk = (const float*)d_in[4];
  const float* sa_bk = (const float*)d_in[5];
  const float* sa_wv = (const float*)d_in[6];
  const float* sa_bv = (const float*)d_in[7];
  const float* sa_wo = (const float*)d_in[8];
  const float* sa_bo = (const float*)d_in[9];
  const float* ca_wq = (const float*)d_in[10];
  const float* ca_bq = (const float*)d_in[11];
  const float* ca_wk = (const float*)d_in[12];
  const float* ca_bk = (const float*)d_in[13];
  const float* ca_wv = (const float*)d_in[14];
  const float* ca_bv = (const float*)d_in[15];
  const float* ca_wo = (const float*)d_in[16];
  const float* ca_bo = (const float*)d_in[17];
  const float* ln1_g = (const float*)d_in[18];
  const float* ln1_b = (const float*)d_in[19];
  const float* ln2_g = (const float*)d_in[20];
  const float* ln2_b = (const float*)d_in[21];
  const float* ln3_g = (const float*)d_in[22];
  const float* ln3_b = (const float*)d_in[23];
  const float* ffn_w1 = (const float*)d_in[24];
  const float* ffn_b1 = (const float*)d_in[25];
  const float* ffn_w2 = (const float*)d_in[26];
  const float* ffn_b2 = (const float*)d_in[27];
  const float* lnf_g  = (const float*)d_in[28];
  const float* lnf_b  = (const float*)d_in[29];
  const float* feat_wq = (const float*)d_in[30];
  const float* feat_bq = (const float*)d_in[31];
  const float* feat_wc = (const float*)d_in[32];
  const float* feat_bc = (const float*)d_in[33];

  // ---- workspace layout
  char* p = (char*)d_ws;
  _Float16* Xh  = (_Float16*)p;  p += 33554432;  // 32768 x 512 fp16 residual stream
  _Float16* Xsh = (_Float16*)p;  p += 4194304;   //  4096 x 512 fp16 (layer-0 x)
  _Float16* Wh  = (_Float16*)p;  p += 16777216;  // fp16 weight arena (2 layers)
  _Float16* qh  = (_Float16*)p;  p += 1048576;   //  1024 x 512 fp16
  _Float16* KV0 = (_Float16*)p;  p += 2097152;   //  1024 x 1024 fp16 (K|V)
  float*    Bqkv = (float*)p;    p += 12288;
  float*    Bkv  = (float*)p;    p += 8192;
  float*    QN  = (float*)p;     p += 8192;
  const size_t fixed_b = (size_t)(p - (char*)d_ws);
  long R = 4096;
  if (ws_size >= fixed_b + 5120UL * 32768) R = 32768;
  else if (ws_size >= fixed_b + 5120UL * 16384) R = 16384;
  else if (ws_size >= fixed_b + 5120UL * 8192) R = 8192;
  _Float16* QKVc = (_Float16*)p; p += R * 3072;  // [R][1536]
  _Float16* Oc   = (_Float16*)p; p += R * 1024;  // [R][512]
  _Float16* Ac   = (_Float16*)p;                 // [R][512]
  _Float16* Hb = QKVc;            // FFN hidden [R][2048] spans QKVc+Oc (contiguous)
  const int MTR = (int)(R / 256);

  // ---- prep (6 launches)
  f2h2<<<10240, 256, 0, stream>>>(c_in, Xsh, 2097152, q_in, qh, 524288);
  tconv512<<<dim3(8, 8, 12), 256, 0, stream>>>(sa_wq, sa_wk, sa_wv, ca_wq, ca_wk, ca_wv, Wh);
  woconvB<<<dim3(1024, 4), 256, 0, stream>>>(sa_wo, ca_wo, Wh);
  tconvL<<<dim3(32, 8, 2), 256, 0, stream>>>(ffn_w1, Wh + 2097152, 512, 2048, 1048576, 4194304);
  tconvL<<<dim3(8, 32, 2), 256, 0, stream>>>(ffn_w2, Wh + 3145728, 2048, 512, 1048576, 4194304);
  packbias<<<20, 256, 0, stream>>>(sa_bq, sa_bk, sa_bv, ca_bk, ca_bv, Bqkv, Bkv);

  // =================== layer 0 (x rows = 4096) ===================
  {
    _Float16* Wl = Wh;
    gemm_h<<<dim3(12, 32), 256, 0, stream>>>(Xsh, Wl + 0, Bqkv, QKVc, 4096, 1536, 512, 1536, 0);
    attn_h<<<256, 256, 0, stream>>>(QKVc, 1536, QKVc + 512, QKVc + 1024, 1536, Oc, 0, 0, 0);
    gemm_h<<<dim3(4, 32), 256, 0, stream>>>(Oc, Wl + 786432, sa_bo, Ac, 4096, 512, 512, 512, 0);
    ln_h<<<1024, 256, 0, stream>>>(c_in, 1, Ac, Xsh, ln1_g, ln1_b, 0, 0x7FFFFFFF);
    gemm_h<<<dim3(4, 32), 256, 0, stream>>>(Xsh, Wl + 1048576, ca_bq, QKVc, 4096, 512, 512, 1536, 0);
    gemm_h<<<dim3(8, 8), 256, 0, stream>>>(qh, Wl + 1310720, Bkv, KV0, 1024, 1024, 512, 1024, 0);
    for (long c = 0; c < 32768; c += R) {
      attn_h<<<(R / 128) * 8, 256, 0, stream>>>(QKVc, 1536, KV0, KV0 + 512, 1024, Oc,
                                                1, 1, (int)(c / 128));
      gemm8<<<MTR * 2, 512, 0, stream>>>(Oc, Wl + 1835008, ca_bo, Ac, MTR, 2, 512, 512, 0);
      ln_h<<<R / 4, 256, 0, stream>>>(Xsh, 0, Ac, Xh, ln2_g, ln2_b, c, 4095);
      gemm8<<<MTR * 8, 512, 0, stream>>>(Xh + c * 512, Wl + 2097152,
                                         ffn_b1, Hb, MTR, 8, 512, 2048, 1);
      gemm8<<<MTR * 2, 512, 0, stream>>>(Hb, Wl + 3145728, ffn_b2, Ac, MTR, 2, 2048, 512, 0);
      ln_h<<<R / 4, 256, 0, stream>>>(Xh, 0, Ac, Xh, ln3_g, ln3_b, c, 0x7FFFFFFF);
    }
  }
  // =================== layer 1 (x rows = 32768) ===================
  {
    _Float16* Wl = Wh + 4194304;
    gemm_h<<<dim3(8, 8), 256, 0, stream>>>(qh, Wl + 1310720, Bkv + 1024, KV0, 1024, 1024, 512, 1024, 0);
    for (long c = 0; c < 32768; c += R) {
      _Float16* Xhc = Xh + c * 512;
      gemm8<<<MTR * 6, 512, 0, stream>>>(Xhc, Wl + 0, Bqkv + 1536, QKVc, MTR, 6, 512, 1536, 0);
      attn_h<<<(R / 128) * 8, 256, 0, stream>>>(QKVc, 1536, QKVc + 512, QKVc + 1024, 1536,
                                                Oc, 0, 0, 0);
      gemm8<<<MTR * 2, 512, 0, stream>>>(Oc, Wl + 786432, sa_bo + 512, Ac, MTR, 2, 512, 512, 0);
      ln_h<<<R / 4, 256, 0, stream>>>(Xh, 0, Ac, Xh, ln1_g + 512, ln1_b + 512, c, 0x7FFFFFFF);
      gemm8<<<MTR * 2, 512, 0, stream>>>(Xhc, Wl + 1048576, ca_bq + 512, QKVc, MTR, 2, 512, 1536, 0);
      attn_h<<<(R / 128) * 8, 256, 0, stream>>>(QKVc, 1536, KV0, KV0 + 512, 1024, Oc,
                                                1, 0, (int)(c / 128));
      gemm8<<<MTR * 2, 512, 0, stream>>>(Oc, Wl + 1835008, ca_bo + 512, Ac, MTR, 2, 512, 512, 0);
      ln_h<<<R / 4, 256, 0, stream>>>(Xh, 0, Ac, Xh, ln2_g + 512, ln2_b + 512, c, 0x7FFFFFFF);
      gemm8<<<MTR * 8, 512, 0, stream>>>(Xh + c * 512, Wl + 2097152,
                                         ffn_b1 + 2048, Hb, MTR, 8, 512, 2048, 1);
      gemm8<<<MTR * 2, 512, 0, stream>>>(Hb, Wl + 3145728, ffn_b2 + 512, Ac, MTR, 2, 2048, 512, 0);
      ln_h<<<R / 4, 256, 0, stream>>>(Xh, 0, Ac, Xh, ln3_g + 512, ln3_b + 512, c, 0x7FFFFFFF);
    }
  }
  // =================== final LN + fused pool/features/cosine ===================
  ln_h<<<8192, 256, 0, stream>>>(Xh, 0, nullptr, Xh, lnf_g, lnf_b, 0, 0x7FFFFFFF);
  featq_pool<<<8, 256, 0, stream>>>(q_in, feat_wq, feat_bq, QN);
  featc_pool<<<256, 256, 0, stream>>>(Xh, feat_wc, feat_bc, QN, (float*)d_out);
}

// Round 5
// 970.673 us; speedup vs baseline: 1.0866x; 1.0175x over previous
//
#include <hip/hip_runtime.h>

using half4  = __attribute__((ext_vector_type(4))) _Float16;
using half8  = __attribute__((ext_vector_type(8))) _Float16;
using floatx4 = __attribute__((ext_vector_type(4))) float;

__device__ __forceinline__ void gl_lds16(const _Float16* g, _Float16* l)
{
  __builtin_amdgcn_global_load_lds(
      (const __attribute__((address_space(1))) void*)g,
      (__attribute__((address_space(3))) void*)l, 16, 0, 0);
}

__device__ __forceinline__ uint32_t lds_u32(const _Float16* p)
{
  return (uint32_t)(uintptr_t)(const __attribute__((address_space(3))) _Float16*)p;
}

// inline-asm LDS read: opaque to compiler waitcnt insertion (otherwise it
// emits vmcnt(0) before LDS reads that might alias pending global_load_lds).
template<int IMM>
__device__ __forceinline__ half8 dsr(uint32_t addr)
{
  half8 r;
  asm volatile("ds_read_b128 %0, %1 offset:%2" : "=v"(r) : "v"(addr), "i"(IMM));
  return r;
}

#define LGK0() do { asm volatile("s_waitcnt lgkmcnt(0)" ::: "memory"); \
                    __builtin_amdgcn_sched_barrier(0); } while (0)
#define VM0()  do { asm volatile("s_waitcnt vmcnt(0)" ::: "memory"); \
                    __builtin_amdgcn_sched_barrier(0); } while (0)

// ---------------- MFMA fp16 GEMM (128x128 tile, BK=32, seg-XOR swizzled)
__global__ __launch_bounds__(256) void gemm_h(
    const _Float16* __restrict__ A, const _Float16* __restrict__ Bt,
    const float* __restrict__ bias, _Float16* __restrict__ C,
    int M, int N, int K, int ldC, int relu)
{
  __shared__ _Float16 As[128 * 32];
  __shared__ _Float16 Bs[128 * 32];
  int tid = threadIdx.x;
  int lane = tid & 63, wave = tid >> 6;
  long bm0 = (long)blockIdx.y * 128;
  int bn0 = blockIdx.x * 128;
  int wm = (wave & 1) * 64, wn = (wave >> 1) * 64;
  int srow = wave * 16 + (lane >> 2);
  int scol = (((lane & 3) ^ ((lane >> 3) & 3)) * 8);
  const _Float16* aA0 = A + (bm0 + srow) * (long)K + scol;
  const _Float16* aA1 = aA0 + 64 * (long)K;
  const _Float16* aB0 = Bt + (bn0 + srow) * (long)K + scol;
  const _Float16* aB1 = aB0 + 64 * (long)K;
  _Float16* lA0 = As + wave * 512;
  _Float16* lA1 = As + 2048 + wave * 512;
  _Float16* lB0 = Bs + wave * 512;
  _Float16* lB1 = Bs + 2048 + wave * 512;
  int mrow = lane & 15, quad = lane >> 4;
  int cofs = (quad ^ ((mrow >> 1) & 3)) * 8;
  floatx4 acc[4][4];
#pragma unroll
  for (int i = 0; i < 4; ++i)
#pragma unroll
    for (int j = 0; j < 4; ++j) acc[i][j] = (floatx4){0.f, 0.f, 0.f, 0.f};

  for (int kt = 0; kt < K; kt += 32) {
    __syncthreads();
    gl_lds16(aA0 + kt, lA0);
    gl_lds16(aA1 + kt, lA1);
    gl_lds16(aB0 + kt, lB0);
    gl_lds16(aB1 + kt, lB1);
    __syncthreads();
    half8 af[4], bf[4];
#pragma unroll
    for (int i = 0; i < 4; ++i)
      af[i] = *(const half8*)&As[(wm + 16 * i + mrow) * 32 + cofs];
#pragma unroll
    for (int j = 0; j < 4; ++j)
      bf[j] = *(const half8*)&Bs[(wn + 16 * j + mrow) * 32 + cofs];
#pragma unroll
    for (int i = 0; i < 4; ++i)
#pragma unroll
      for (int j = 0; j < 4; ++j)
        acc[i][j] = __builtin_amdgcn_mfma_f32_16x16x32_f16(af[i], bf[j], acc[i][j], 0, 0, 0);
  }
#pragma unroll
  for (int j = 0; j < 4; ++j) {
    int n = bn0 + wn + 16 * j + mrow;
    float bj = bias[n];
#pragma unroll
    for (int i = 0; i < 4; ++i) {
#pragma unroll
      for (int r = 0; r < 4; ++r) {
        long m = bm0 + wm + 16 * i + quad * 4 + r;
        float v = acc[i][j][r] + bj;
        if (relu) v = fmaxf(v, 0.f);
        C[m * (long)ldC + n] = (_Float16)v;
      }
    }
  }
}

// ---------------- MFMA fp16 GEMM (256x128 tile, BK=32, double-buffered 48KB,
//  stage-issue at tile start, 1 barrier/tile, asm ds_read, XCD-banded remap)
__global__ __launch_bounds__(256, 2) void gemm_d(
    const _Float16* __restrict__ A, const _Float16* __restrict__ Bt,
    const float* __restrict__ bias, _Float16* __restrict__ C,
    int MT, int NT, int K, int ldC, int relu)
{
  // layout (bytes): buf0 A @0 (16KB), buf0 B @16384 (8KB),
  //                 buf1 A @24576,    buf1 B @40960   -> 48KB total
  __shared__ _Float16 S[24576];
  int tid = threadIdx.x;
  int lane = tid & 63, wave = tid >> 6;
  int L = blockIdx.x;
  int xcd = L & 7, seq = L >> 3;
  int band = MT >> 3;                 // MT is a multiple of 8 at all call sites
  int mt = xcd * band + seq / NT;
  int nt = seq - (seq / NT) * NT;
  long bm0 = (long)mt * 256;
  int bn0 = nt * 128;
  // staging addresses (gemm_h's verified BK=32 swizzle pair)
  int srow = lane >> 2;
  int scol = (((lane & 3) ^ ((lane >> 3) & 3)) * 8);
  const _Float16* aA = A + (bm0 + wave * 64 + srow) * (long)K + scol;
  const _Float16* aB = Bt + (bn0 + wave * 32 + srow) * (long)K + scol;
  _Float16* lA = S + (wave * 64) * 32;            // 4 insts x 16 rows per wave
  _Float16* lB = S + 8192 + (wave * 32) * 32;     // 2 insts x 16 rows per wave
  int mrow = lane & 15, quad = lane >> 4;
  int cofs = (quad ^ ((mrow >> 1) & 3)) * 8;
  // byte-unit LDS read bases
  uint32_t abase = lds_u32(S) + (uint32_t)((wave * 64 + mrow) * 32 + cofs) * 2u;
  uint32_t bbase = lds_u32(S) + 16384u + (uint32_t)(mrow * 32 + cofs) * 2u;
  floatx4 acc[4][8];
#pragma unroll
  for (int i = 0; i < 4; ++i)
#pragma unroll
    for (int j = 0; j < 8; ++j) acc[i][j] = (floatx4){0.f, 0.f, 0.f, 0.f};

  int NTK = K >> 5;
  // prologue: stage tile 0 into buf0, publish
#pragma unroll
  for (int o = 0; o < 4; ++o)
    gl_lds16(aA + (long)(o * 16) * K, lA + o * 512);
#pragma unroll
  for (int o = 0; o < 2; ++o)
    gl_lds16(aB + (long)(o * 16) * K, lB + o * 512);
  VM0();
  __builtin_amdgcn_s_barrier();

  for (int t = 0; t < NTK; ++t) {
    // current buffer byte offset: buf1 starts at byte 24576 (element 12288)
    uint32_t db = (t & 1) ? 24576u : 0u;
    // issue next tile into the dead buffer FIRST: full-tile flight time
    __builtin_amdgcn_sched_barrier(0);
    if (t + 1 < NTK) {
      uint32_t nb = ((t + 1) & 1) ? 24576u : 0u;   // bytes; element = bytes/2
      _Float16* nA = S + nb / 2;
      _Float16* nB = nA + 8192;
      int kt = (t + 1) << 5;
#pragma unroll
      for (int o = 0; o < 4; ++o)
        gl_lds16(aA + kt + (long)(o * 16) * K, nA + (wave * 64) * 32 + o * 512);
#pragma unroll
      for (int o = 0; o < 2; ++o)
        gl_lds16(aB + kt + (long)(o * 16) * K, nB + (wave * 32) * 32 + o * 512);
    }
    __builtin_amdgcn_sched_barrier(0);
    // fragment reads from current buffer (asm: no compiler vmcnt injected)
    uint32_t a = abase + db, b = bbase + db;
    half8 af[4], bf[8];
    af[0] = dsr<0>(a);    af[1] = dsr<1024>(a);
    af[2] = dsr<2048>(a); af[3] = dsr<3072>(a);
    bf[0] = dsr<0>(b);    bf[1] = dsr<1024>(b);
    bf[2] = dsr<2048>(b); bf[3] = dsr<3072>(b);
    bf[4] = dsr<4096>(b); bf[5] = dsr<5120>(b);
    bf[6] = dsr<6144>(b); bf[7] = dsr<7168>(b);
    LGK0();
    __builtin_amdgcn_s_setprio(1);
#pragma unroll
    for (int i = 0; i < 4; ++i)       // 32 independent MFMAs
#pragma unroll
      for (int j = 0; j < 8; ++j)
        acc[i][j] = __builtin_amdgcn_mfma_f32_16x16x32_f16(af[i], bf[j], acc[i][j], 0, 0, 0);
    __builtin_amdgcn_s_setprio(0);
    __builtin_amdgcn_sched_barrier(0);
    // next tile's 6 loads were issued a whole tile ago -> near-zero wait
    VM0();
    __builtin_amdgcn_s_barrier();
  }
#pragma unroll
  for (int j = 0; j < 8; ++j) {
    int n = bn0 + 16 * j + mrow;
    float bj = bias[n];
#pragma unroll
    for (int i = 0; i < 4; ++i) {
#pragma unroll
      for (int r = 0; r < 4; ++r) {
        long m = bm0 + wave * 64 + 16 * i + quad * 4 + r;
        float v = acc[i][j][r] + bj;
        if (relu) v = fmaxf(v, 0.f);
        C[m * (long)ldC + n] = (_Float16)v;
      }
    }
  }
}

// ---------------- MFMA fused attention (V prefetched into registers)
__global__ __launch_bounds__(256) void attn_h(
    const _Float16* __restrict__ Qp, int qs,
    const _Float16* __restrict__ Kp, const _Float16* __restrict__ Vp, int ks,
    _Float16* __restrict__ Op, int mode_ca, int l0, int rb0)
{
  __shared__ _Float16 KV[128 * 72];
  __shared__ _Float16 Ps[128 * 136];
  int tid = threadIdx.x;
  int lane = tid & 63, wave = tid >> 6;
  int ll = lane & 15, quad = lane >> 4;
  int idx = blockIdx.x;
  int n = idx & 7;
  int rl = idx >> 3;
  long obase = (long)rl * 128 * 512 + n * 64;
  long qoff, koff;
  if (!mode_ca) {
    qoff = (long)rl * 128 * qs + n * 64;
    koff = (long)rl * 128 * ks + n * 64;
  } else {
    int g = rb0 + rl;
    int a = g >> 5;
    int qblk = l0 ? (g & 31) : rl;
    qoff = (long)qblk * 128 * qs + n * 64;
    koff = (long)a * 128 * ks + n * 64;
  }
  // stage K tile; prefetch Q and V from global before first barrier
#pragma unroll
  for (int it = 0; it < 4; ++it) {
    int e = tid + it * 256;
    int r = e >> 3, c = (e & 7) * 8;
    *(half8*)&KV[r * 72 + c] = *(const half8*)&Kp[koff + (long)r * ks + c];
  }
  half8 aQ[2][2];
#pragma unroll
  for (int i = 0; i < 2; ++i)
#pragma unroll
    for (int k2 = 0; k2 < 2; ++k2)
      aQ[i][k2] = *(const half8*)&Qp[qoff + (long)(wave * 32 + i * 16 + ll) * qs
                                     + quad * 8 + k2 * 32];
  half8 vreg[4];
#pragma unroll
  for (int it = 0; it < 4; ++it) {
    int e = tid + it * 256;
    int vr = e >> 3, c = (e & 7) * 8;
    vreg[it] = *(const half8*)&Vp[koff + (long)vr * ks + c];
  }
  __syncthreads();
  floatx4 accS[2][8];
#pragma unroll
  for (int i = 0; i < 2; ++i)
#pragma unroll
    for (int j = 0; j < 8; ++j) accS[i][j] = (floatx4){0.f, 0.f, 0.f, 0.f};
#pragma unroll
  for (int k2 = 0; k2 < 2; ++k2) {
#pragma unroll
    for (int j = 0; j < 8; ++j) {
      half8 bK = *(const half8*)&KV[(j * 16 + ll) * 72 + quad * 8 + k2 * 32];
      accS[0][j] = __builtin_amdgcn_mfma_f32_16x16x32_f16(aQ[0][k2], bK, accS[0][j], 0, 0, 0);
      accS[1][j] = __builtin_amdgcn_mfma_f32_16x16x32_f16(aQ[1][k2], bK, accS[1][j], 0, 0, 0);
    }
  }
  float rinv[2][4];
#pragma unroll
  for (int i = 0; i < 2; ++i) {
#pragma unroll
    for (int r = 0; r < 4; ++r) {
      float mx = -1e30f;
#pragma unroll
      for (int j = 0; j < 8; ++j) {
        accS[i][j][r] *= 0.125f;
        mx = fmaxf(mx, accS[i][j][r]);
      }
#pragma unroll
      for (int off = 1; off < 16; off <<= 1) mx = fmaxf(mx, __shfl_xor(mx, off));
      float s = 0.f;
#pragma unroll
      for (int j = 0; j < 8; ++j) {
        float e = __expf(accS[i][j][r] - mx);
        accS[i][j][r] = e;
        s += e;
      }
#pragma unroll
      for (int off = 1; off < 16; off <<= 1) s += __shfl_xor(s, off);
      rinv[i][r] = 1.f / s;
      int prow = wave * 32 + i * 16 + quad * 4 + r;
#pragma unroll
      for (int j = 0; j < 8; ++j)
        Ps[prow * 136 + j * 16 + ll] = (_Float16)accS[i][j][r];
    }
  }
  __syncthreads();   // K reads done; Ps visible
  // write prefetched V transposed: Vt[h][seq] at KV[h*132 + seq]
#pragma unroll
  for (int it = 0; it < 4; ++it) {
    int e = tid + it * 256;
    int vr = e >> 3, c = (e & 7) * 8;
#pragma unroll
    for (int j = 0; j < 8; ++j) KV[(c + j) * 132 + vr] = vreg[it][j];
  }
  __syncthreads();
  floatx4 accO[2][4];
#pragma unroll
  for (int i = 0; i < 2; ++i)
#pragma unroll
    for (int j = 0; j < 4; ++j) accO[i][j] = (floatx4){0.f, 0.f, 0.f, 0.f};
#pragma unroll
  for (int k4 = 0; k4 < 4; ++k4) {
    half8 aP[2];
#pragma unroll
    for (int i = 0; i < 2; ++i)
      aP[i] = *(const half8*)&Ps[(wave * 32 + i * 16 + ll) * 136 + quad * 8 + k4 * 32];
#pragma unroll
    for (int jh = 0; jh < 4; ++jh) {
      int vb = (jh * 16 + ll) * 132 + quad * 8 + k4 * 32;
      half4 v0 = *(const half4*)&KV[vb];
      half4 v1 = *(const half4*)&KV[vb + 4];
      half8 bV = __builtin_shufflevector(v0, v1, 0, 1, 2, 3, 4, 5, 6, 7);
      accO[0][jh] = __builtin_amdgcn_mfma_f32_16x16x32_f16(aP[0], bV, accO[0][jh], 0, 0, 0);
      accO[1][jh] = __builtin_amdgcn_mfma_f32_16x16x32_f16(aP[1], bV, accO[1][jh], 0, 0, 0);
    }
  }
#pragma unroll
  for (int i = 0; i < 2; ++i)
#pragma unroll
    for (int jh = 0; jh < 4; ++jh)
#pragma unroll
      for (int r = 0; r < 4; ++r) {
        int m = wave * 32 + i * 16 + quad * 4 + r;
        Op[obase + (long)m * 512 + jh * 16 + ll] = (_Float16)(accO[i][jh][r] * rinv[i][r]);
      }
}

// ---------------- Residual + LayerNorm (rows of 512, fp32 math). One wave per row.
__global__ __launch_bounds__(256) void ln_h(
    const void* __restrict__ xin, int xf32, const _Float16* __restrict__ add,
    _Float16* __restrict__ out, const float* __restrict__ g,
    const float* __restrict__ bt, long row0, int bmask)
{
  int rl = blockIdx.x * 4 + (threadIdx.x >> 6);
  long row = row0 + rl;
  int lane = threadIdx.x & 63;
  long xr = (row & (long)bmask) * 512 + lane * 8;
  float v[8];
  if (xf32) {
    float4 a0 = *(const float4*)((const float*)xin + xr);
    float4 a1 = *(const float4*)((const float*)xin + xr + 4);
    v[0] = a0.x; v[1] = a0.y; v[2] = a0.z; v[3] = a0.w;
    v[4] = a1.x; v[5] = a1.y; v[6] = a1.z; v[7] = a1.w;
  } else {
    half8 h = *(const half8*)((const _Float16*)xin + xr);
#pragma unroll
    for (int i = 0; i < 8; ++i) v[i] = (float)h[i];
  }
  if (add) {
    half8 a = *(const half8*)&add[(long)rl * 512 + lane * 8];
#pragma unroll
    for (int i = 0; i < 8; ++i) v[i] += (float)a[i];
  }
  float s = 0.f, sq = 0.f;
#pragma unroll
  for (int i = 0; i < 8; ++i) { s += v[i]; sq += v[i] * v[i]; }
#pragma unroll
  for (int off = 1; off < 64; off <<= 1) {
    s += __shfl_xor(s, off);
    sq += __shfl_xor(sq, off);
  }
  float mean = s * (1.f / 512.f);
  float var = sq * (1.f / 512.f) - mean * mean;
  float rst = rsqrtf(var + 1e-6f);
  int c = lane * 8;
  float4 g0 = *(const float4*)&g[c], g1 = *(const float4*)&g[c + 4];
  float4 b0 = *(const float4*)&bt[c], b1 = *(const float4*)&bt[c + 4];
  float gg[8] = {g0.x, g0.y, g0.z, g0.w, g1.x, g1.y, g1.z, g1.w};
  float bb[8] = {b0.x, b0.y, b0.z, b0.w, b1.x, b1.y, b1.z, b1.w};
  half8 o;
#pragma unroll
  for (int i = 0; i < 8; ++i) o[i] = (_Float16)((v[i] - mean) * rst * gg[i] + bb[i]);
  *(half8*)&out[row * 512 + c] = o;
}

// ---------------- batched 512x512 transpose-convert (12 weights in one launch)
__global__ __launch_bounds__(256) void tconv512(
    const float* __restrict__ w0, const float* __restrict__ w1,
    const float* __restrict__ w2, const float* __restrict__ w3,
    const float* __restrict__ w4, const float* __restrict__ w5,
    _Float16* __restrict__ Wh)
{
  __shared__ float T[64][65];
  int z = blockIdx.z;
  int t = z >> 1, l = z & 1;
  const float* src;
  long off;
  switch (t) {
    case 0: src = w0; off = 0; break;
    case 1: src = w1; off = 262144; break;
    case 2: src = w2; off = 524288; break;
    case 3: src = w3; off = 1048576; break;
    case 4: src = w4; off = 1310720; break;
    default: src = w5; off = 1572864; break;
  }
  src += (long)l * 262144;
  _Float16* out = Wh + (long)l * 4194304 + off;
  int tx = threadIdx.x & 63, tg = threadIdx.x >> 6;
  int r0 = blockIdx.y * 64, c0 = blockIdx.x * 64;
#pragma unroll
  for (int i = 0; i < 16; ++i)
    T[tg + 4 * i][tx] = src[(long)(r0 + tg + 4 * i) * 512 + c0 + tx];
  __syncthreads();
#pragma unroll
  for (int i = 0; i < 16; ++i)
    out[(long)(c0 + tg + 4 * i) * 512 + r0 + tx] = (_Float16)T[tx][tg + 4 * i];
}

// ---------------- layered transpose-convert for FFN weights
__global__ __launch_bounds__(256) void tconvL(const float* __restrict__ in,
                                              _Float16* __restrict__ out, int Rr, int Cc,
                                              long ils, long ols)
{
  __shared__ float T[64][65];
  in += (long)blockIdx.z * ils;
  out += (long)blockIdx.z * ols;
  int tx = threadIdx.x & 63, tg = threadIdx.x >> 6;
  int r0 = blockIdx.y * 64, c0 = blockIdx.x * 64;
#pragma unroll
  for (int i = 0; i < 16; ++i)
    T[tg + 4 * i][tx] = in[(long)(r0 + tg + 4 * i) * Cc + c0 + tx];
  __syncthreads();
#pragma unroll
  for (int i = 0; i < 16; ++i)
    out[(long)(c0 + tg + 4 * i) * Rr + r0 + tx] = (_Float16)T[tx][tg + 4 * i];
}

// ---------------- batched wo conversion
__global__ void woconvB(const float* __restrict__ sa_wo, const float* __restrict__ ca_wo,
                        _Float16* __restrict__ Wh)
{
  int z = blockIdx.y;
  int s = z >> 1, l = z & 1;
  const float* wo = (s ? ca_wo : sa_wo) + (long)l * 262144;
  _Float16* out = Wh + (long)l * 4194304 + (s ? 1835008 : 786432);
  int o = blockIdx.x * 256 + threadIdx.x;  // 262144
  int d = o >> 9;
  int nh = o & 511;
  int n = nh >> 6, h = nh & 63;
  out[o] = (_Float16)wo[((long)(n << 9) + d) * 64 + h];
}

// ---------------- pack all biases in one launch
__global__ void packbias(const float* __restrict__ sa_bq, const float* __restrict__ sa_bk,
                         const float* __restrict__ sa_bv, const float* __restrict__ ca_bk,
                         const float* __restrict__ ca_bv, float* __restrict__ Bqkv,
                         float* __restrict__ Bkv)
{
  int i = blockIdx.x * 256 + threadIdx.x;
  if (i >= 5120) return;
  int reg = i >> 9, idx = i & 511;
  int l = reg / 5, r = reg % 5;
  int lo = l * 512;
  switch (r) {
    case 0: Bqkv[l * 1536 + idx] = sa_bq[lo + idx]; break;
    case 1: Bqkv[l * 1536 + 512 + idx] = sa_bk[lo + idx]; break;
    case 2: Bqkv[l * 1536 + 1024 + idx] = sa_bv[lo + idx]; break;
    case 3: Bkv[l * 1024 + idx] = ca_bk[lo + idx]; break;
    default: Bkv[l * 1024 + 512 + idx] = ca_bv[lo + idx]; break;
  }
}

// ---------------- fused fp32->fp16 for c and q
__global__ void f2h2(const float* __restrict__ a, _Float16* __restrict__ oa, long na,
                     const float* __restrict__ bsrc, _Float16* __restrict__ ob, long nb)
{
  long i = blockIdx.x * 256L + threadIdx.x;
  if (i < na) oa[i] = (_Float16)a[i];
  else if (i < na + nb) ob[i - na] = (_Float16)bsrc[i - na];
}

// ---------------- fused pool(q fp32) + feature + normalize -> QN (8 x 256)
__global__ void featq_pool(const float* __restrict__ q, const float* __restrict__ W,
                           const float* __restrict__ bias, float* __restrict__ QN)
{
  __shared__ float sh[512];
  __shared__ float red[256];
  int a = blockIdx.x;
  int f = threadIdx.x;
  for (int dd = f; dd < 512; dd += 256) {
    const float* base = q + (long)a * 65536 + dd;
    float s = 0.f;
    for (int t = 1; t < 128; ++t) s += base[t * 512];
    sh[dd] = s * (1.f / 127.f);
  }
  __syncthreads();
  float acc = bias[f];
  for (int d = 0; d < 512; ++d) acc += sh[d] * W[d * 256 + f];
  red[f] = acc * acc;
  __syncthreads();
  for (int s = 128; s > 0; s >>= 1) {
    if (f < s) red[f] += red[f + s];
    __syncthreads();
  }
  float rn = rsqrtf(fmaxf(red[0], 1e-12f));
  QN[a * 256 + f] = acc * rn;
}

// ---------------- fused pool(X fp16) + feature + normalize + dot(QN) -> out (256)
__global__ void featc_pool(const _Float16* __restrict__ X, const float* __restrict__ W,
                           const float* __restrict__ bias, const float* __restrict__ QN,
                           float* __restrict__ out)
{
  __shared__ float sh[512];
  __shared__ float red[256];
  int ab = blockIdx.x;
  int f = threadIdx.x;
  for (int dd = f; dd < 512; dd += 256) {
    const _Float16* base = X + (long)ab * 65536 + dd;
    float s = 0.f;
    for (int t = 1; t < 128; ++t) s += (float)base[t * 512];
    sh[dd] = s * (1.f / 127.f);
  }
  __syncthreads();
  float acc = bias[f];
  for (int d = 0; d < 512; ++d) acc += sh[d] * W[d * 256 + f];
  red[f] = acc * acc;
  __syncthreads();
  for (int s = 128; s > 0; s >>= 1) {
    if (f < s) red[f] += red[f + s];
    __syncthreads();
  }
  float rn = rsqrtf(fmaxf(red[0], 1e-12f));
  float v = acc * rn * QN[(ab >> 5) * 256 + f];
  __syncthreads();
  red[f] = v;
  __syncthreads();
  for (int s = 128; s > 0; s >>= 1) {
    if (f < s) red[f] += red[f + s];
    __syncthreads();
  }
  if (f == 0) out[ab] = red[0];
}

extern "C" void kernel_launch(void* const* d_in, const int* in_sizes, int n_in,
                              void* d_out, int out_size, void* d_ws, size_t ws_size,
                              hipStream_t stream)
{
  (void)in_sizes; (void)n_in; (void)out_size;
  const float* c_in  = (const float*)d_in[0];
  const float* q_in  = (const float*)d_in[1];
  const float* sa_wq = (const float*)d_in[2];
  const float* sa_bq = (const float*)d_in[3];
  const float* sa_wk = (const float*)d_in[4];
  const float* sa_bk = (const float*)d_in[5];
  const float* sa_wv = (const float*)d_in[6];
  const float* sa_bv = (const float*)d_in[7];
  const float* sa_wo = (const float*)d_in[8];
  const float* sa_bo = (const float*)d_in[9];
  const float* ca_wq = (const float*)d_in[10];
  const float* ca_bq = (const float*)d_in[11];
  const float* ca_wk = (const float*)d_in[12];
  const float* ca_bk = (const float*)d_in[13];
  const float* ca_wv = (const float*)d_in[14];
  const float* ca_bv = (const float*)d_in[15];
  const float* ca_wo = (const float*)d_in[16];
  const float* ca_bo = (const float*)d_in[17];
  const float* ln1_g = (const float*)d_in[18];
  const float* ln1_b = (const float*)d_in[19];
  const float* ln2_g = (const float*)d_in[20];
  const float* ln2_b = (const float*)d_in[21];
  const float* ln3_g = (const float*)d_in[22];
  const float* ln3_b = (const float*)d_in[23];
  const float* ffn_w1 = (const float*)d_in[24];
  const float* ffn_b1 = (const float*)d_in[25];
  const float* ffn_w2 = (const float*)d_in[26];
  const float* ffn_b2 = (const float*)d_in[27];
  const float* lnf_g  = (const float*)d_in[28];
  const float* lnf_b  = (const float*)d_in[29];
  const float* feat_wq = (const float*)d_in[30];
  const float* feat_bq = (const float*)d_in[31];
  const float* feat_wc = (const float*)d_in[32];
  const float* feat_bc = (const float*)d_in[33];

  // ---- workspace layout
  char* p = (char*)d_ws;
  _Float16* Xh  = (_Float16*)p;  p += 33554432;  // 32768 x 512 fp16 residual stream
  _Float16* Xsh = (_Float16*)p;  p += 4194304;   //  4096 x 512 fp16 (layer-0 x)
  _Float16* Wh  = (_Float16*)p;  p += 16777216;  // fp16 weight arena (2 layers)
  _Float16* qh  = (_Float16*)p;  p += 1048576;   //  1024 x 512 fp16
  _Float16* KV0 = (_Float16*)p;  p += 2097152;   //  1024 x 1024 fp16 (K|V)
  float*    Bqkv = (float*)p;    p += 12288;
  float*    Bkv  = (float*)p;    p += 8192;
  float*    QN  = (float*)p;     p += 8192;
  const size_t fixed_b = (size_t)(p - (char*)d_ws);
  long R = 4096;
  if (ws_size >= fixed_b + 5120UL * 32768) R = 32768;
  else if (ws_size >= fixed_b + 5120UL * 16384) R = 16384;
  else if (ws_size >= fixed_b + 5120UL * 8192) R = 8192;
  _Float16* QKVc = (_Float16*)p; p += R * 3072;  // [R][1536]
  _Float16* Oc   = (_Float16*)p; p += R * 1024;  // [R][512]
  _Float16* Ac   = (_Float16*)p;                 // [R][512]
  _Float16* Hb = QKVc;            // FFN hidden [R][2048] spans QKVc+Oc (contiguous)
  const int MTR = (int)(R / 256);

  // ---- prep (6 launches)
  f2h2<<<10240, 256, 0, stream>>>(c_in, Xsh, 2097152, q_in, qh, 524288);
  tconv512<<<dim3(8, 8, 12), 256, 0, stream>>>(sa_wq, sa_wk, sa_wv, ca_wq, ca_wk, ca_wv, Wh);
  woconvB<<<dim3(1024, 4), 256, 0, stream>>>(sa_wo, ca_wo, Wh);
  tconvL<<<dim3(32, 8, 2), 256, 0, stream>>>(ffn_w1, Wh + 2097152, 512, 2048, 1048576, 4194304);
  tconvL<<<dim3(8, 32, 2), 256, 0, stream>>>(ffn_w2, Wh + 3145728, 2048, 512, 1048576, 4194304);
  packbias<<<20, 256, 0, stream>>>(sa_bq, sa_bk, sa_bv, ca_bk, ca_bv, Bqkv, Bkv);

  // =================== layer 0 (x rows = 4096) ===================
  {
    _Float16* Wl = Wh;
    gemm_h<<<dim3(12, 32), 256, 0, stream>>>(Xsh, Wl + 0, Bqkv, QKVc, 4096, 1536, 512, 1536, 0);
    attn_h<<<256, 256, 0, stream>>>(QKVc, 1536, QKVc + 512, QKVc + 1024, 1536, Oc, 0, 0, 0);
    gemm_h<<<dim3(4, 32), 256, 0, stream>>>(Oc, Wl + 786432, sa_bo, Ac, 4096, 512, 512, 512, 0);
    ln_h<<<1024, 256, 0, stream>>>(c_in, 1, Ac, Xsh, ln1_g, ln1_b, 0, 0x7FFFFFFF);
    gemm_h<<<dim3(4, 32), 256, 0, stream>>>(Xsh, Wl + 1048576, ca_bq, QKVc, 4096, 512, 512, 1536, 0);
    gemm_h<<<dim3(8, 8), 256, 0, stream>>>(qh, Wl + 1310720, Bkv, KV0, 1024, 1024, 512, 1024, 0);
    for (long c = 0; c < 32768; c += R) {
      attn_h<<<(R / 128) * 8, 256, 0, stream>>>(QKVc, 1536, KV0, KV0 + 512, 1024, Oc,
                                                1, 1, (int)(c / 128));
      gemm_d<<<MTR * 4, 256, 0, stream>>>(Oc, Wl + 1835008, ca_bo, Ac, MTR, 4, 512, 512, 0);
      ln_h<<<R / 4, 256, 0, stream>>>(Xsh, 0, Ac, Xh, ln2_g, ln2_b, c, 4095);
      gemm_d<<<MTR * 16, 256, 0, stream>>>(Xh + c * 512, Wl + 2097152,
                                           ffn_b1, Hb, MTR, 16, 512, 2048, 1);
      gemm_d<<<MTR * 4, 256, 0, stream>>>(Hb, Wl + 3145728, ffn_b2, Ac, MTR, 4, 2048, 512, 0);
      ln_h<<<R / 4, 256, 0, stream>>>(Xh, 0, Ac, Xh, ln3_g, ln3_b, c, 0x7FFFFFFF);
    }
  }
  // =================== layer 1 (x rows = 32768) ===================
  {
    _Float16* Wl = Wh + 4194304;
    gemm_h<<<dim3(8, 8), 256, 0, stream>>>(qh, Wl + 1310720, Bkv + 1024, KV0, 1024, 1024, 512, 1024, 0);
    for (long c = 0; c < 32768; c += R) {
      _Float16* Xhc = Xh + c * 512;
      gemm_d<<<MTR * 12, 256, 0, stream>>>(Xhc, Wl + 0, Bqkv + 1536, QKVc, MTR, 12, 512, 1536, 0);
      attn_h<<<(R / 128) * 8, 256, 0, stream>>>(QKVc, 1536, QKVc + 512, QKVc + 1024, 1536,
                                                Oc, 0, 0, 0);
      gemm_d<<<MTR * 4, 256, 0, stream>>>(Oc, Wl + 786432, sa_bo + 512, Ac, MTR, 4, 512, 512, 0);
      ln_h<<<R / 4, 256, 0, stream>>>(Xh, 0, Ac, Xh, ln1_g + 512, ln1_b + 512, c, 0x7FFFFFFF);
      gemm_d<<<MTR * 4, 256, 0, stream>>>(Xhc, Wl + 1048576, ca_bq + 512, QKVc, MTR, 4, 512, 1536, 0);
      attn_h<<<(R / 128) * 8, 256, 0, stream>>>(QKVc, 1536, KV0, KV0 + 512, 1024, Oc,
                                                1, 0, (int)(c / 128));
      gemm_d<<<MTR * 4, 256, 0, stream>>>(Oc, Wl + 1835008, ca_bo + 512, Ac, MTR, 4, 512, 512, 0);
      ln_h<<<R / 4, 256, 0, stream>>>(Xh, 0, Ac, Xh, ln2_g + 512, ln2_b + 512, c, 0x7FFFFFFF);
      gemm_d<<<MTR * 16, 256, 0, stream>>>(Xh + c * 512, Wl + 2097152,
                                           ffn_b1 + 2048, Hb, MTR, 16, 512, 2048, 1);
      gemm_d<<<MTR * 4, 256, 0, stream>>>(Hb, Wl + 3145728, ffn_b2 + 512, Ac, MTR, 4, 2048, 512, 0);
      ln_h<<<R / 4, 256, 0, stream>>>(Xh, 0, Ac, Xh, ln3_g + 512, ln3_b + 512, c, 0x7FFFFFFF);
    }
  }
  // =================== final LN + fused pool/features/cosine ===================
  ln_h<<<8192, 256, 0, stream>>>(Xh, 0, nullptr, Xh, lnf_g, lnf_b, 0, 0x7FFFFFFF);
  featq_pool<<<8, 256, 0, stream>>>(q_in, feat_wq, feat_bq, QN);
  featc_pool<<<256, 256, 0, stream>>>(Xh, feat_wc, feat_bc, QN, (float*)d_out);
}